// Round 3
// baseline (303.177 us; speedup 1.0000x reference)
//
#include <hip/hip_runtime.h>
#include <math.h>

// SS2D (VMamba v2) forward — MI355X gfx950, fp32 throughout.
//
// Pipeline (6 dispatches):
//  k_setup  : W_in -> WtIn (96x384), W_out -> WtOut (192x96), zero scan flags
//  k_inproj : xz = x @ W_in^T ; xin = xz[:,:192], z = silu(xz[:,192:])
//  k_conv8  : depthwise 3x3 SAME + bias + silu, 8-pixel row tiles -> xg (scan order)
//  k_xdbl   : LDS-tiled GEMM per (bk, 64-l tile): 38x192 @ 192x64 -> dtr/Bm/Cm
//  k_scan   : single-pass chunked scan (32 chunks of 32) w/ decoupled lookback
//  k_lnout  : merge + LayerNorm(192) + gate(z) + out GEMM (fused)

#define DINNER 192
#define NSTATE 16
#define KDIR 4
#define BATCH 4
#define NPIX (BATCH * 64 * 64)          // 16384
#define LP 1024
#define NCH 32                          // scan chunks
#define CHUNK 32                        // LP / NCH
#define NBK (BATCH * KDIR)              // 16
#define PQSTRIDE (DINNER * NSTATE)      // 3072 floats per chunk-block

__device__ __forceinline__ float silu_f(float x) {
    return x / (1.0f + __expf(-x));
}
__device__ __forceinline__ float softplus_f(float a) {
    return (a > 20.0f) ? a : __logf(1.0f + __expf(a));
}

__global__ __launch_bounds__(256) void k_setup(
        const float* __restrict__ W_in, const float* __restrict__ W_out,
        float* __restrict__ WtIn, float* __restrict__ WtOut,
        int* __restrict__ flags) {
    int i = blockIdx.x * 256 + threadIdx.x;
    if (i < 96 * 384) {               // WtIn[c*384+e] = W_in[e*96+c]
        int c = i / 384, e = i % 384;
        WtIn[i] = W_in[e * 96 + c];
    }
    if (i < 192 * 96) {               // WtOut[d*96+o] = W_out[o*192+d]
        int d = i / 96, o = i % 96;
        WtOut[i] = W_out[o * 192 + d];
    }
    if (i < NBK * NCH) flags[i] = 0;
}

// 32 pixels/block; thread (pi=t>>6, ei=t&63) -> acc over 6 e-groups x 8 pixels
__global__ __launch_bounds__(256) void k_inproj(
        const float* __restrict__ x, const float* __restrict__ WtIn,
        float* __restrict__ xin, float* __restrict__ z) {
    __shared__ float xs[32 * 96];
    int p0 = blockIdx.x * 32;
    int t = threadIdx.x;
    for (int i = t; i < 32 * 96; i += 256) xs[i] = x[p0 * 96 + i];
    __syncthreads();
    int ei = t & 63;
    int pi = t >> 6;
    float acc[6][8];
    #pragma unroll
    for (int j = 0; j < 6; ++j)
        #pragma unroll
        for (int pp = 0; pp < 8; ++pp) acc[j][pp] = 0.0f;
    for (int c = 0; c < 96; ++c) {
        float wv[6];
        #pragma unroll
        for (int j = 0; j < 6; ++j) wv[j] = WtIn[c * 384 + j * 64 + ei];
        #pragma unroll
        for (int pp = 0; pp < 8; ++pp) {
            float xv = xs[(pi * 8 + pp) * 96 + c];
            #pragma unroll
            for (int j = 0; j < 6; ++j) acc[j][pp] = fmaf(wv[j], xv, acc[j][pp]);
        }
    }
    #pragma unroll
    for (int j = 0; j < 6; ++j) {
        int e = j * 64 + ei;
        #pragma unroll
        for (int pp = 0; pp < 8; ++pp) {
            int p = p0 + pi * 8 + pp;
            if (e < 192) xin[p * 192 + e] = acc[j][pp];
            else         z[p * 192 + (e - 192)] = silu_f(acc[j][pp]);
        }
    }
}

// depthwise 3x3, 8 consecutive pixels of one row per block; sliding-window loads.
// Output in scan order xg[(bk*1024+l)*192+d].
__global__ __launch_bounds__(192) void k_conv8(
        const float* __restrict__ xin, const float* __restrict__ cw,
        const float* __restrict__ cb, float* __restrict__ xg) {
    int blk = blockIdx.x;             // 2048 = 4 b * 64 h * 8 wchunks
    int b = blk >> 9;
    int rem = blk & 511;
    int h = rem >> 3;
    int w0 = (rem & 7) * 8;
    int d = threadIdx.x;
    float wr[3][3];
    #pragma unroll
    for (int i = 0; i < 3; ++i)
        #pragma unroll
        for (int j = 0; j < 3; ++j) wr[i][j] = cw[d * 9 + i * 3 + j];
    float bias = cb[d];
    float acc[8];
    #pragma unroll
    for (int o = 0; o < 8; ++o) acc[o] = bias;
    #pragma unroll
    for (int jj = 0; jj < 10; ++jj) {
        int ww = w0 + jj - 1;
        float r0 = 0.0f, r1 = 0.0f, r2 = 0.0f;
        if ((unsigned)ww < 64u) {
            const float* base = xin + ((size_t)b * 4096 + h * 64 + ww) * 192 + d;
            if (h > 0)  r0 = base[-64 * 192];
            r1 = base[0];
            if (h < 63) r2 = base[64 * 192];
        }
        // column (w0+jj-1) feeds outputs o = jj-2 (tap 2), jj-1 (tap 1), jj (tap 0)
        #pragma unroll
        for (int dd2 = 0; dd2 < 3; ++dd2) {
            int o = jj - 2 + dd2;
            int cj = 2 - dd2;
            if (o >= 0 && o < 8) {
                acc[o] = fmaf(r0, wr[0][cj], acc[o]);
                acc[o] = fmaf(r1, wr[1][cj], acc[o]);
                acc[o] = fmaf(r2, wr[2][cj], acc[o]);
            }
        }
    }
    #pragma unroll
    for (int o = 0; o < 8; ++o) {
        int w = w0 + o;
        int kq = (h & 1) ? ((w & 1) ? 3 : 1) : ((w & 1) ? 2 : 0);
        int l = (kq & 1) ? ((w >> 1) * 32 + (h >> 1))
                         : ((h >> 1) * 32 + (w >> 1));
        xg[((size_t)(b * 4 + kq) * 1024 + l) * 192 + d] = silu_f(acc[o]);
    }
}

// GEMM 38x192 @ 192x64 per block. W in LDS (broadcast), X in LDS (stride 194).
__global__ __launch_bounds__(256) void k_xdbl(
        const float* __restrict__ xg, const float* __restrict__ xpw,
        float* __restrict__ dtr, float* __restrict__ Bm, float* __restrict__ Cm) {
    __shared__ float sW[40 * 192];     // rows 38,39 zero
    __shared__ float sX[64 * 194];
    int bk = blockIdx.x >> 4;
    int tile = blockIdx.x & 15;
    int k = bk & 3;
    int t = threadIdx.x;
    const float4* wsrc = (const float4*)(xpw + k * 38 * 192);
    for (int i = t; i < 40 * 48; i += 256) {
        float4 v = make_float4(0.f, 0.f, 0.f, 0.f);
        if (i < 38 * 48) v = wsrc[i];
        ((float4*)sW)[i] = v;
    }
    const float2* xsrc = (const float2*)(xg + (size_t)(bk * 1024 + tile * 64) * 192);
    for (int i = t; i < 64 * 96; i += 256) {
        int f = i * 2;
        int row = f / 192, col = f - row * 192;
        *(float2*)&sX[row * 194 + col] = xsrc[i];
    }
    __syncthreads();
    int l = t & 63, w = t >> 6;
    int cbase = w * 10;
    float acc[10];
    #pragma unroll
    for (int i = 0; i < 10; ++i) acc[i] = 0.0f;
    #pragma unroll 4
    for (int q = 0; q < 96; ++q) {
        float2 xv = *(const float2*)&sX[l * 194 + 2 * q];
        #pragma unroll
        for (int ci = 0; ci < 10; ++ci) {
            float2 wv = *(const float2*)&sW[(cbase + ci) * 192 + 2 * q];
            acc[ci] = fmaf(xv.x, wv.x, fmaf(xv.y, wv.y, acc[ci]));
        }
    }
    int bkl = bk * 1024 + tile * 64 + l;
    #pragma unroll
    for (int ci = 0; ci < 10; ++ci) {
        int c = cbase + ci;
        if (c < 38) {
            float v = acc[ci];
            if (c < 6)       dtr[bkl * 6 + c] = v;
            else if (c < 22) Bm[bkl * 16 + (c - 6)] = v;
            else             Cm[bkl * 16 + (c - 22)] = v;
        }
    }
}

// Single-pass chunked scan with decoupled lookback.
// Block = (bk, ch). Pass A: local (P, Q) with h_in=0, publish + flag.
// Lookback: compose predecessors' (P,Q) in order. Pass B: replay, emit y.
__global__ __launch_bounds__(192) void k_scan(
        const float* __restrict__ dtr, const float* __restrict__ xg,
        const float* __restrict__ Bm, const float* __restrict__ Cm,
        const float* __restrict__ A_logs, const float* __restrict__ dtw,
        const float* __restrict__ dtb, const float* __restrict__ Ds,
        float* __restrict__ Pbuf, float* __restrict__ Qbuf,
        int* __restrict__ flags, float* __restrict__ yout) {
    __shared__ float sD[CHUNK * 192];   // delta cache (per-thread column)
    __shared__ float sB[CHUNK * 16];
    __shared__ float sC[CHUNK * 16];
    int bk = blockIdx.x >> 5;
    int ch = blockIdx.x & 31;
    int k = bk & 3;
    int d = threadIdx.x;
    float A[16];
    #pragma unroll
    for (int n = 0; n < 16; ++n) A[n] = -__expf(A_logs[(k * 192 + d) * 16 + n]);
    float wp[6];
    #pragma unroll
    for (int q = 0; q < 6; ++q) wp[q] = dtw[(k * 192 + d) * 6 + q];
    float bias = dtb[k * 192 + d];
    float Dp = Ds[k * 192 + d];
    int lbase = bk * 1024 + ch * CHUNK;
    for (int i = d; i < CHUNK * 16; i += 192) {
        sB[i] = Bm[lbase * 16 + i];
        sC[i] = Cm[lbase * 16 + i];
    }
    __syncthreads();
    // ---- Pass A ----
    float h[16], P[16];
    #pragma unroll
    for (int n = 0; n < 16; ++n) { h[n] = 0.0f; P[n] = 1.0f; }
    for (int l = 0; l < CHUNK; ++l) {
        const float* r = dtr + (size_t)(lbase + l) * 6;
        float a = bias;
        #pragma unroll
        for (int q = 0; q < 6; ++q) a = fmaf(wp[q], r[q], a);
        float dlt = softplus_f(a);
        sD[l * 192 + d] = dlt;
        float u = xg[(size_t)(lbase + l) * 192 + d];
        float du = dlt * u;
        #pragma unroll
        for (int n = 0; n < 16; ++n) {
            float e = __expf(dlt * A[n]);
            h[n] = fmaf(e, h[n], du * sB[l * 16 + n]);
            P[n] *= e;
        }
    }
    {
        size_t base = (size_t)blockIdx.x * PQSTRIDE;
        #pragma unroll
        for (int n = 0; n < 16; ++n) {
            Pbuf[base + n * 192 + d] = P[n];
            Qbuf[base + n * 192 + d] = h[n];
        }
    }
    __threadfence();
    __syncthreads();
    if (d == 0)
        __hip_atomic_store(&flags[blockIdx.x], 1, __ATOMIC_RELEASE,
                           __HIP_MEMORY_SCOPE_AGENT);
    // ---- Lookback ----
    #pragma unroll
    for (int n = 0; n < 16; ++n) h[n] = 0.0f;
    if (ch > 0) {
        if (d < ch) {
            while (__hip_atomic_load(&flags[bk * 32 + d], __ATOMIC_ACQUIRE,
                                     __HIP_MEMORY_SCOPE_AGENT) == 0) {
                __builtin_amdgcn_s_sleep(2);
            }
        }
        __syncthreads();
        __threadfence();
        for (int j = 0; j < ch; ++j) {
            const float* Pj = Pbuf + (size_t)(bk * 32 + j) * PQSTRIDE;
            const float* Qj = Qbuf + (size_t)(bk * 32 + j) * PQSTRIDE;
            #pragma unroll
            for (int n = 0; n < 16; ++n)
                h[n] = fmaf(Pj[n * 192 + d], h[n], Qj[n * 192 + d]);
        }
    }
    // ---- Pass B ----
    for (int l = 0; l < CHUNK; ++l) {
        float dlt = sD[l * 192 + d];
        float u = xg[(size_t)(lbase + l) * 192 + d];
        float du = dlt * u;
        float y = 0.0f;
        #pragma unroll
        for (int n = 0; n < 16; ++n) {
            float e = __expf(dlt * A[n]);
            h[n] = fmaf(e, h[n], du * sB[l * 16 + n]);
            y = fmaf(h[n], sC[l * 16 + n], y);
        }
        yout[(size_t)(lbase + l) * 192 + d] = fmaf(u, Dp, y);
    }
}

// Fused: merge + LayerNorm(192) + gate(z) + out GEMM. 32 pixels/block.
__global__ __launch_bounds__(256) void k_lnout(
        const float* __restrict__ yout, const float* __restrict__ z,
        const float* __restrict__ lng, const float* __restrict__ lnb,
        const float* __restrict__ WoT, float* __restrict__ out) {
    __shared__ float sg[32 * 196];     // stride 196 floats (784B, 16B-aligned)
    int p0 = blockIdx.x * 32;
    int t = threadIdx.x;
    int p = t >> 3;                    // pixel 0..31
    int sub = t & 7;                   // 8 threads per pixel, 24 channels each
    // pixel -> (bk, l)
    int gp = p0 + p;
    int b = gp >> 12;
    int hw = gp & 4095;
    int h = hw >> 6, w = hw & 63;
    int kq = (h & 1) ? ((w & 1) ? 3 : 1) : ((w & 1) ? 2 : 0);
    int l = (kq & 1) ? ((w >> 1) * 32 + (h >> 1))
                     : ((h >> 1) * 32 + (w >> 1));
    const float* yrow = yout + ((size_t)(b * 4 + kq) * 1024 + l) * 192 + sub * 24;
    float4 yv[6];
    float s = 0.0f, s2 = 0.0f;
    #pragma unroll
    for (int j = 0; j < 6; ++j) {
        yv[j] = *(const float4*)(yrow + j * 4 * 1);  // contiguous 24 floats
    }
    // note: yrow + j*4 floats
    #pragma unroll
    for (int j = 0; j < 6; ++j) {
        float4 v = *(const float4*)(yrow + j * 4);
        yv[j] = v;
        s += v.x + v.y + v.z + v.w;
        s2 += v.x * v.x + v.y * v.y + v.z * v.z + v.w * v.w;
    }
    // halve double-count (loop above executed once for sums; first loop discarded)
    // reduce over the 8 threads of this pixel (lanes 8p..8p+7)
    #pragma unroll
    for (int off = 1; off < 8; off <<= 1) {
        s  += __shfl_xor(s, off, 8);
        s2 += __shfl_xor(s2, off, 8);
    }
    float mu = s * (1.0f / 192.0f);
    float var = s2 * (1.0f / 192.0f) - mu * mu;
    float rstd = rsqrtf(var + 1e-5f);
    const float* zrow = z + (size_t)gp * 192 + sub * 24;
    float* grow = sg + p * 196 + sub * 24;
    #pragma unroll
    for (int j = 0; j < 6; ++j) {
        float4 zv = *(const float4*)(zrow + j * 4);
        float4 gv = *(const float4*)(lng + sub * 24 + j * 4);
        float4 bv = *(const float4*)(lnb + sub * 24 + j * 4);
        float4 o;
        o.x = ((yv[j].x - mu) * rstd * gv.x + bv.x) * zv.x;
        o.y = ((yv[j].y - mu) * rstd * gv.y + bv.y) * zv.y;
        o.z = ((yv[j].z - mu) * rstd * gv.z + bv.z) * zv.z;
        o.w = ((yv[j].w - mu) * rstd * gv.w + bv.w) * zv.w;
        *(float4*)(grow + j * 4) = o;
    }
    __syncthreads();
    // GEMM phase: out[32 pix x 96] = g @ WoT
    int oi = t & 31, wi = t >> 5;
    float acc[4][3];
    #pragma unroll
    for (int pp = 0; pp < 4; ++pp)
        #pragma unroll
        for (int j = 0; j < 3; ++j) acc[pp][j] = 0.0f;
    for (int dd = 0; dd < 192; dd += 4) {
        float4 q0 = *(const float4*)&sg[(wi * 4 + 0) * 196 + dd];
        float4 q1 = *(const float4*)&sg[(wi * 4 + 1) * 196 + dd];
        float4 q2 = *(const float4*)&sg[(wi * 4 + 2) * 196 + dd];
        float4 q3 = *(const float4*)&sg[(wi * 4 + 3) * 196 + dd];
        #pragma unroll
        for (int r = 0; r < 4; ++r) {
            float w0 = WoT[(dd + r) * 96 + oi];
            float w1 = WoT[(dd + r) * 96 + oi + 32];
            float w2 = WoT[(dd + r) * 96 + oi + 64];
            float e0 = (r == 0) ? q0.x : (r == 1) ? q0.y : (r == 2) ? q0.z : q0.w;
            float e1 = (r == 0) ? q1.x : (r == 1) ? q1.y : (r == 2) ? q1.z : q1.w;
            float e2 = (r == 0) ? q2.x : (r == 1) ? q2.y : (r == 2) ? q2.z : q2.w;
            float e3 = (r == 0) ? q3.x : (r == 1) ? q3.y : (r == 2) ? q3.z : q3.w;
            acc[0][0] = fmaf(e0, w0, acc[0][0]);
            acc[0][1] = fmaf(e0, w1, acc[0][1]);
            acc[0][2] = fmaf(e0, w2, acc[0][2]);
            acc[1][0] = fmaf(e1, w0, acc[1][0]);
            acc[1][1] = fmaf(e1, w1, acc[1][1]);
            acc[1][2] = fmaf(e1, w2, acc[1][2]);
            acc[2][0] = fmaf(e2, w0, acc[2][0]);
            acc[2][1] = fmaf(e2, w1, acc[2][1]);
            acc[2][2] = fmaf(e2, w2, acc[2][2]);
            acc[3][0] = fmaf(e3, w0, acc[3][0]);
            acc[3][1] = fmaf(e3, w1, acc[3][1]);
            acc[3][2] = fmaf(e3, w2, acc[3][2]);
        }
    }
    #pragma unroll
    for (int pp = 0; pp < 4; ++pp)
        #pragma unroll
        for (int j = 0; j < 3; ++j)
            out[(size_t)(p0 + wi * 4 + pp) * 96 + oi + 32 * j] = acc[pp][j];
}

extern "C" void kernel_launch(void* const* d_in, const int* in_sizes, int n_in,
                              void* d_out, int out_size, void* d_ws, size_t ws_size,
                              hipStream_t stream) {
    const float* x    = (const float*)d_in[0];
    const float* W_in = (const float*)d_in[1];
    const float* cw   = (const float*)d_in[2];
    const float* cb   = (const float*)d_in[3];
    const float* xpw  = (const float*)d_in[4];
    const float* dtw  = (const float*)d_in[5];
    const float* dtb  = (const float*)d_in[6];
    const float* Alog = (const float*)d_in[7];
    const float* Ds   = (const float*)d_in[8];
    const float* lng  = (const float*)d_in[9];
    const float* lnb  = (const float*)d_in[10];
    const float* Wout = (const float*)d_in[11];
    float* out = (float*)d_out;

    float* ws = (float*)d_ws;
    size_t off = 0;
    float* WtIn  = ws + off; off += 96 * 384;
    float* WtOut = ws + off; off += 192 * 96;
    int*   flags = (int*)(ws + off); off += 512;
    float* xin   = ws + off; off += (size_t)NPIX * 192;
    float* zbuf  = ws + off; off += (size_t)NPIX * 192;
    float* xg    = ws + off; off += (size_t)NPIX * 192;
    float* dtr   = ws + off; off += (size_t)NBK * LP * 6;
    float* Bm    = ws + off; off += (size_t)NBK * LP * 16;
    float* Cm    = ws + off; off += (size_t)NBK * LP * 16;
    float* Pbuf  = ws + off; off += (size_t)NBK * NCH * PQSTRIDE;
    float* Qbuf  = ws + off; off += (size_t)NBK * NCH * PQSTRIDE;
    float* yout  = ws + off; off += (size_t)NBK * LP * 192;

    hipLaunchKernelGGL(k_setup, dim3(144), dim3(256), 0, stream,
                       W_in, Wout, WtIn, WtOut, flags);
    hipLaunchKernelGGL(k_inproj, dim3(NPIX / 32), dim3(256), 0, stream,
                       x, WtIn, xin, zbuf);
    hipLaunchKernelGGL(k_conv8, dim3(NPIX / 8), dim3(192), 0, stream,
                       xin, cw, cb, xg);
    hipLaunchKernelGGL(k_xdbl, dim3(NBK * 16), dim3(256), 0, stream,
                       xg, xpw, dtr, Bm, Cm);
    hipLaunchKernelGGL(k_scan, dim3(NBK * NCH), dim3(192), 0, stream,
                       dtr, xg, Bm, Cm, Alog, dtw, dtb, Ds,
                       Pbuf, Qbuf, flags, yout);
    hipLaunchKernelGGL(k_lnout, dim3(NPIX / 32), dim3(256), 0, stream,
                       yout, zbuf, lng, lnb, WtOut, out);
}

// Round 4
// 203.717 us; speedup vs baseline: 1.4882x; 1.4882x over previous
//
#include <hip/hip_runtime.h>
#include <math.h>

// SS2D (VMamba v2) forward — MI355X gfx950, fp32 throughout.
//
// Pipeline (8 dispatches):
//  k_setup  : W_in -> WtIn (96x384), W_out -> WtOut (192x96)
//  k_inproj : xz = x @ W_in^T ; xin = xz[:,:192], z = silu(xz[:,192:])
//  k_conv8  : depthwise 3x3 SAME + bias + silu, 8-pixel row tiles -> xg (scan order)
//  k_xdbl   : LDS-tiled GEMM per (bk, 64-l tile): 38x192 @ 192x64 -> dtr/Bm/Cm
//  k_scan1  : per 16-step chunk: (P, Q) with h_in = 0   [inputs LDS-staged]
//  k_scan2  : prefix over 64 chunks per state (in place QH -> h at chunk start)
//  k_scan3  : replay chunk with true h_in, emit y        [inputs LDS-staged]
//  k_lnout  : merge + LayerNorm(192) + gate(z) + out GEMM (fused)

#define DINNER 192
#define NSTATE 16
#define KDIR 4
#define BATCH 4
#define NPIX (BATCH * 64 * 64)          // 16384
#define LP 1024
#define NCH 64                          // scan chunks
#define CHUNK 16                        // LP / NCH
#define NBK (BATCH * KDIR)              // 16
#define NSTATES (NBK * DINNER * NSTATE) // 49152

__device__ __forceinline__ float silu_f(float x) {
    return x / (1.0f + __expf(-x));
}
__device__ __forceinline__ float softplus_f(float a) {
    return (a > 20.0f) ? a : __logf(1.0f + __expf(a));
}

__global__ __launch_bounds__(256) void k_setup(
        const float* __restrict__ W_in, const float* __restrict__ W_out,
        float* __restrict__ WtIn, float* __restrict__ WtOut) {
    int i = blockIdx.x * 256 + threadIdx.x;
    if (i < 96 * 384) {               // WtIn[c*384+e] = W_in[e*96+c]
        int c = i / 384, e = i % 384;
        WtIn[i] = W_in[e * 96 + c];
    }
    if (i < 192 * 96) {               // WtOut[d*96+o] = W_out[o*192+d]
        int d = i / 96, o = i % 96;
        WtOut[i] = W_out[o * 192 + d];
    }
}

// 32 pixels/block; thread (pi=t>>6, ei=t&63) -> acc over 6 e-groups x 8 pixels
__global__ __launch_bounds__(256) void k_inproj(
        const float* __restrict__ x, const float* __restrict__ WtIn,
        float* __restrict__ xin, float* __restrict__ z) {
    __shared__ float xs[32 * 96];
    int p0 = blockIdx.x * 32;
    int t = threadIdx.x;
    for (int i = t; i < 32 * 96; i += 256) xs[i] = x[p0 * 96 + i];
    __syncthreads();
    int ei = t & 63;
    int pi = t >> 6;
    float acc[6][8];
    #pragma unroll
    for (int j = 0; j < 6; ++j)
        #pragma unroll
        for (int pp = 0; pp < 8; ++pp) acc[j][pp] = 0.0f;
    for (int c = 0; c < 96; ++c) {
        float wv[6];
        #pragma unroll
        for (int j = 0; j < 6; ++j) wv[j] = WtIn[c * 384 + j * 64 + ei];
        #pragma unroll
        for (int pp = 0; pp < 8; ++pp) {
            float xv = xs[(pi * 8 + pp) * 96 + c];
            #pragma unroll
            for (int j = 0; j < 6; ++j) acc[j][pp] = fmaf(wv[j], xv, acc[j][pp]);
        }
    }
    #pragma unroll
    for (int j = 0; j < 6; ++j) {
        int e = j * 64 + ei;
        #pragma unroll
        for (int pp = 0; pp < 8; ++pp) {
            int p = p0 + pi * 8 + pp;
            if (e < 192) xin[p * 192 + e] = acc[j][pp];
            else         z[p * 192 + (e - 192)] = silu_f(acc[j][pp]);
        }
    }
}

// depthwise 3x3, 8 consecutive pixels of one row per block; sliding-window loads.
// Output in scan order xg[(bk*1024+l)*192+d].
__global__ __launch_bounds__(192) void k_conv8(
        const float* __restrict__ xin, const float* __restrict__ cw,
        const float* __restrict__ cb, float* __restrict__ xg) {
    int blk = blockIdx.x;             // 2048 = 4 b * 64 h * 8 wchunks
    int b = blk >> 9;
    int rem = blk & 511;
    int h = rem >> 3;
    int w0 = (rem & 7) * 8;
    int d = threadIdx.x;
    float wr[3][3];
    #pragma unroll
    for (int i = 0; i < 3; ++i)
        #pragma unroll
        for (int j = 0; j < 3; ++j) wr[i][j] = cw[d * 9 + i * 3 + j];
    float bias = cb[d];
    float acc[8];
    #pragma unroll
    for (int o = 0; o < 8; ++o) acc[o] = bias;
    #pragma unroll
    for (int jj = 0; jj < 10; ++jj) {
        int ww = w0 + jj - 1;
        float r0 = 0.0f, r1 = 0.0f, r2 = 0.0f;
        if ((unsigned)ww < 64u) {
            const float* base = xin + ((size_t)b * 4096 + h * 64 + ww) * 192 + d;
            if (h > 0)  r0 = base[-64 * 192];
            r1 = base[0];
            if (h < 63) r2 = base[64 * 192];
        }
        #pragma unroll
        for (int dd2 = 0; dd2 < 3; ++dd2) {
            int o = jj - 2 + dd2;
            int cj = 2 - dd2;
            if (o >= 0 && o < 8) {
                acc[o] = fmaf(r0, wr[0][cj], acc[o]);
                acc[o] = fmaf(r1, wr[1][cj], acc[o]);
                acc[o] = fmaf(r2, wr[2][cj], acc[o]);
            }
        }
    }
    #pragma unroll
    for (int o = 0; o < 8; ++o) {
        int w = w0 + o;
        int kq = (h & 1) ? ((w & 1) ? 3 : 1) : ((w & 1) ? 2 : 0);
        int l = (kq & 1) ? ((w >> 1) * 32 + (h >> 1))
                         : ((h >> 1) * 32 + (w >> 1));
        xg[((size_t)(b * 4 + kq) * 1024 + l) * 192 + d] = silu_f(acc[o]);
    }
}

// GEMM 38x192 @ 192x64 per block. W in LDS (broadcast), X in LDS (stride 194).
__global__ __launch_bounds__(256) void k_xdbl(
        const float* __restrict__ xg, const float* __restrict__ xpw,
        float* __restrict__ dtr, float* __restrict__ Bm, float* __restrict__ Cm) {
    __shared__ float sW[40 * 192];     // rows 38,39 zero
    __shared__ float sX[64 * 194];
    int bk = blockIdx.x >> 4;
    int tile = blockIdx.x & 15;
    int k = bk & 3;
    int t = threadIdx.x;
    const float4* wsrc = (const float4*)(xpw + k * 38 * 192);
    for (int i = t; i < 40 * 48; i += 256) {
        float4 v = make_float4(0.f, 0.f, 0.f, 0.f);
        if (i < 38 * 48) v = wsrc[i];
        ((float4*)sW)[i] = v;
    }
    const float2* xsrc = (const float2*)(xg + (size_t)(bk * 1024 + tile * 64) * 192);
    for (int i = t; i < 64 * 96; i += 256) {
        int f = i * 2;
        int row = f / 192, col = f - row * 192;
        *(float2*)&sX[row * 194 + col] = xsrc[i];
    }
    __syncthreads();
    int l = t & 63, w = t >> 6;
    int cbase = w * 10;
    float acc[10];
    #pragma unroll
    for (int i = 0; i < 10; ++i) acc[i] = 0.0f;
    #pragma unroll 4
    for (int q = 0; q < 96; ++q) {
        float2 xv = *(const float2*)&sX[l * 194 + 2 * q];
        #pragma unroll
        for (int ci = 0; ci < 10; ++ci) {
            float2 wv = *(const float2*)&sW[(cbase + ci) * 192 + 2 * q];
            acc[ci] = fmaf(xv.x, wv.x, fmaf(xv.y, wv.y, acc[ci]));
        }
    }
    int bkl = bk * 1024 + tile * 64 + l;
    #pragma unroll
    for (int ci = 0; ci < 10; ++ci) {
        int c = cbase + ci;
        if (c < 38) {
            float v = acc[ci];
            if (c < 6)       dtr[bkl * 6 + c] = v;
            else if (c < 22) Bm[bkl * 16 + (c - 6)] = v;
            else             Cm[bkl * 16 + (c - 22)] = v;
        }
    }
}

// Pass 1: per chunk, P = prod(dA), Q = h after chunk with h_in = 0.
// All chunk inputs bulk-staged in LDS; recurrence loop touches LDS+regs only.
__global__ __launch_bounds__(192) void k_scan1(
        const float* __restrict__ dtr, const float* __restrict__ xg,
        const float* __restrict__ Bm, const float* __restrict__ A_logs,
        const float* __restrict__ dtw, const float* __restrict__ dtb,
        float* __restrict__ Pbuf, float* __restrict__ Qbuf) {
    __shared__ float sU[CHUNK * 192];
    __shared__ float sB[CHUNK * 16];
    __shared__ float sR[CHUNK * 6];
    int bk = blockIdx.x >> 6;
    int ch = blockIdx.x & 63;
    int k = bk & 3;
    int d = threadIdx.x;
    int lbase = bk * 1024 + ch * CHUNK;
    const float4* usrc = (const float4*)(xg + (size_t)lbase * 192);
    for (int i = d; i < CHUNK * 48; i += 192) ((float4*)sU)[i] = usrc[i];
    for (int i = d; i < CHUNK * 16; i += 192) sB[i] = Bm[lbase * 16 + i];
    if (d < CHUNK * 6) sR[d] = dtr[lbase * 6 + d];
    float A[16];
    #pragma unroll
    for (int n = 0; n < 16; ++n) A[n] = -__expf(A_logs[(k * 192 + d) * 16 + n]);
    float wp[6];
    #pragma unroll
    for (int q = 0; q < 6; ++q) wp[q] = dtw[(k * 192 + d) * 6 + q];
    float bias = dtb[k * 192 + d];
    __syncthreads();
    float h[16], P[16];
    #pragma unroll
    for (int n = 0; n < 16; ++n) { h[n] = 0.0f; P[n] = 1.0f; }
    for (int l = 0; l < CHUNK; ++l) {
        float a = bias;
        #pragma unroll
        for (int q = 0; q < 6; ++q) a = fmaf(wp[q], sR[l * 6 + q], a);
        float dlt = softplus_f(a);
        float du = dlt * sU[l * 192 + d];
        #pragma unroll
        for (int n = 0; n < 16; ++n) {
            float e = __expf(dlt * A[n]);
            h[n] = fmaf(e, h[n], du * sB[l * 16 + n]);
            P[n] *= e;
        }
    }
    size_t base = (size_t)ch * NSTATES + bk * (192 * 16);
    #pragma unroll
    for (int n = 0; n < 16; ++n) {
        Pbuf[base + n * 192 + d] = P[n];
        Qbuf[base + n * 192 + d] = h[n];
    }
}

// Pass 2: prefix over chunks (in place: QH becomes h at chunk start).
__global__ __launch_bounds__(256) void k_scan2(
        const float* __restrict__ Pbuf, float* QH) {
    int s = blockIdx.x * 256 + threadIdx.x;
    float h = 0.0f;
    #pragma unroll 4
    for (int c = 0; c < NCH; ++c) {
        float q = QH[(size_t)c * NSTATES + s];
        float p = Pbuf[(size_t)c * NSTATES + s];
        QH[(size_t)c * NSTATES + s] = h;
        h = fmaf(p, h, q);
    }
}

// Pass 3: replay with correct h_in, emit y.
__global__ __launch_bounds__(192) void k_scan3(
        const float* __restrict__ dtr, const float* __restrict__ xg,
        const float* __restrict__ Bm, const float* __restrict__ Cm,
        const float* __restrict__ A_logs, const float* __restrict__ dtw,
        const float* __restrict__ dtb, const float* __restrict__ Ds,
        const float* __restrict__ QH, float* __restrict__ yout) {
    __shared__ float sU[CHUNK * 192];
    __shared__ float sB[CHUNK * 16];
    __shared__ float sC[CHUNK * 16];
    __shared__ float sR[CHUNK * 6];
    int bk = blockIdx.x >> 6;
    int ch = blockIdx.x & 63;
    int k = bk & 3;
    int d = threadIdx.x;
    int lbase = bk * 1024 + ch * CHUNK;
    const float4* usrc = (const float4*)(xg + (size_t)lbase * 192);
    for (int i = d; i < CHUNK * 48; i += 192) ((float4*)sU)[i] = usrc[i];
    for (int i = d; i < CHUNK * 16; i += 192) {
        sB[i] = Bm[lbase * 16 + i];
        sC[i] = Cm[lbase * 16 + i];
    }
    if (d < CHUNK * 6) sR[d] = dtr[lbase * 6 + d];
    float A[16];
    #pragma unroll
    for (int n = 0; n < 16; ++n) A[n] = -__expf(A_logs[(k * 192 + d) * 16 + n]);
    float wp[6];
    #pragma unroll
    for (int q = 0; q < 6; ++q) wp[q] = dtw[(k * 192 + d) * 6 + q];
    float bias = dtb[k * 192 + d];
    float Dp = Ds[k * 192 + d];
    float h[16];
    size_t base = (size_t)ch * NSTATES + bk * (192 * 16);
    #pragma unroll
    for (int n = 0; n < 16; ++n) h[n] = QH[base + n * 192 + d];
    __syncthreads();
    for (int l = 0; l < CHUNK; ++l) {
        float a = bias;
        #pragma unroll
        for (int q = 0; q < 6; ++q) a = fmaf(wp[q], sR[l * 6 + q], a);
        float dlt = softplus_f(a);
        float u = sU[l * 192 + d];
        float du = dlt * u;
        float y = 0.0f;
        #pragma unroll
        for (int n = 0; n < 16; ++n) {
            float e = __expf(dlt * A[n]);
            h[n] = fmaf(e, h[n], du * sB[l * 16 + n]);
            y = fmaf(h[n], sC[l * 16 + n], y);
        }
        yout[(size_t)(lbase + l) * 192 + d] = fmaf(u, Dp, y);
    }
}

// Fused: merge + LayerNorm(192) + gate(z) + out GEMM. 32 pixels/block.
__global__ __launch_bounds__(256) void k_lnout(
        const float* __restrict__ yout, const float* __restrict__ z,
        const float* __restrict__ lng, const float* __restrict__ lnb,
        const float* __restrict__ WoT, float* __restrict__ out) {
    __shared__ float sg[32 * 196];     // stride 196 floats (784B, 16B-aligned)
    int p0 = blockIdx.x * 32;
    int t = threadIdx.x;
    int p = t >> 3;                    // pixel 0..31
    int sub = t & 7;                   // 8 threads per pixel, 24 channels each
    int gp = p0 + p;
    int b = gp >> 12;
    int hw = gp & 4095;
    int h = hw >> 6, w = hw & 63;
    int kq = (h & 1) ? ((w & 1) ? 3 : 1) : ((w & 1) ? 2 : 0);
    int l = (kq & 1) ? ((w >> 1) * 32 + (h >> 1))
                     : ((h >> 1) * 32 + (w >> 1));
    const float* yrow = yout + ((size_t)(b * 4 + kq) * 1024 + l) * 192 + sub * 24;
    float4 yv[6];
    float s = 0.0f, s2 = 0.0f;
    #pragma unroll
    for (int j = 0; j < 6; ++j) {
        float4 v = *(const float4*)(yrow + j * 4);
        yv[j] = v;
        s += v.x + v.y + v.z + v.w;
        s2 += v.x * v.x + v.y * v.y + v.z * v.z + v.w * v.w;
    }
    #pragma unroll
    for (int off = 1; off < 8; off <<= 1) {
        s  += __shfl_xor(s, off, 8);
        s2 += __shfl_xor(s2, off, 8);
    }
    float mu = s * (1.0f / 192.0f);
    float var = s2 * (1.0f / 192.0f) - mu * mu;
    float rstd = rsqrtf(var + 1e-5f);
    const float* zrow = z + (size_t)gp * 192 + sub * 24;
    float* grow = sg + p * 196 + sub * 24;
    #pragma unroll
    for (int j = 0; j < 6; ++j) {
        float4 zv = *(const float4*)(zrow + j * 4);
        float4 gv = *(const float4*)(lng + sub * 24 + j * 4);
        float4 bv = *(const float4*)(lnb + sub * 24 + j * 4);
        float4 o;
        o.x = ((yv[j].x - mu) * rstd * gv.x + bv.x) * zv.x;
        o.y = ((yv[j].y - mu) * rstd * gv.y + bv.y) * zv.y;
        o.z = ((yv[j].z - mu) * rstd * gv.z + bv.z) * zv.z;
        o.w = ((yv[j].w - mu) * rstd * gv.w + bv.w) * zv.w;
        *(float4*)(grow + j * 4) = o;
    }
    __syncthreads();
    int oi = t & 31, wi = t >> 5;
    float acc[4][3];
    #pragma unroll
    for (int pp = 0; pp < 4; ++pp)
        #pragma unroll
        for (int j = 0; j < 3; ++j) acc[pp][j] = 0.0f;
    for (int dd = 0; dd < 192; dd += 4) {
        float4 q0 = *(const float4*)&sg[(wi * 4 + 0) * 196 + dd];
        float4 q1 = *(const float4*)&sg[(wi * 4 + 1) * 196 + dd];
        float4 q2 = *(const float4*)&sg[(wi * 4 + 2) * 196 + dd];
        float4 q3 = *(const float4*)&sg[(wi * 4 + 3) * 196 + dd];
        #pragma unroll
        for (int r = 0; r < 4; ++r) {
            float w0 = WoT[(dd + r) * 96 + oi];
            float w1 = WoT[(dd + r) * 96 + oi + 32];
            float w2 = WoT[(dd + r) * 96 + oi + 64];
            float e0 = (r == 0) ? q0.x : (r == 1) ? q0.y : (r == 2) ? q0.z : q0.w;
            float e1 = (r == 0) ? q1.x : (r == 1) ? q1.y : (r == 2) ? q1.z : q1.w;
            float e2 = (r == 0) ? q2.x : (r == 1) ? q2.y : (r == 2) ? q2.z : q2.w;
            float e3 = (r == 0) ? q3.x : (r == 1) ? q3.y : (r == 2) ? q3.z : q3.w;
            acc[0][0] = fmaf(e0, w0, acc[0][0]);
            acc[0][1] = fmaf(e0, w1, acc[0][1]);
            acc[0][2] = fmaf(e0, w2, acc[0][2]);
            acc[1][0] = fmaf(e1, w0, acc[1][0]);
            acc[1][1] = fmaf(e1, w1, acc[1][1]);
            acc[1][2] = fmaf(e1, w2, acc[1][2]);
            acc[2][0] = fmaf(e2, w0, acc[2][0]);
            acc[2][1] = fmaf(e2, w1, acc[2][1]);
            acc[2][2] = fmaf(e2, w2, acc[2][2]);
            acc[3][0] = fmaf(e3, w0, acc[3][0]);
            acc[3][1] = fmaf(e3, w1, acc[3][1]);
            acc[3][2] = fmaf(e3, w2, acc[3][2]);
        }
    }
    #pragma unroll
    for (int pp = 0; pp < 4; ++pp)
        #pragma unroll
        for (int j = 0; j < 3; ++j)
            out[(size_t)(p0 + wi * 4 + pp) * 96 + oi + 32 * j] = acc[pp][j];
}

extern "C" void kernel_launch(void* const* d_in, const int* in_sizes, int n_in,
                              void* d_out, int out_size, void* d_ws, size_t ws_size,
                              hipStream_t stream) {
    const float* x    = (const float*)d_in[0];
    const float* W_in = (const float*)d_in[1];
    const float* cw   = (const float*)d_in[2];
    const float* cb   = (const float*)d_in[3];
    const float* xpw  = (const float*)d_in[4];
    const float* dtw  = (const float*)d_in[5];
    const float* dtb  = (const float*)d_in[6];
    const float* Alog = (const float*)d_in[7];
    const float* Ds   = (const float*)d_in[8];
    const float* lng  = (const float*)d_in[9];
    const float* lnb  = (const float*)d_in[10];
    const float* Wout = (const float*)d_in[11];
    float* out = (float*)d_out;

    float* ws = (float*)d_ws;
    size_t off = 0;
    float* WtIn  = ws + off; off += 96 * 384;
    float* WtOut = ws + off; off += 192 * 96;
    float* xin   = ws + off; off += (size_t)NPIX * 192;
    float* zbuf  = ws + off; off += (size_t)NPIX * 192;
    float* xg    = ws + off; off += (size_t)NPIX * 192;
    float* dtr   = ws + off; off += (size_t)NBK * LP * 6;
    float* Bm    = ws + off; off += (size_t)NBK * LP * 16;
    float* Cm    = ws + off; off += (size_t)NBK * LP * 16;
    float* Pbuf  = ws + off; off += (size_t)NCH * NSTATES;
    float* QH    = ws + off; off += (size_t)NCH * NSTATES;
    float* yout  = ws + off; off += (size_t)NBK * LP * 192;

    hipLaunchKernelGGL(k_setup, dim3(144), dim3(256), 0, stream,
                       W_in, Wout, WtIn, WtOut);
    hipLaunchKernelGGL(k_inproj, dim3(NPIX / 32), dim3(256), 0, stream,
                       x, WtIn, xin, zbuf);
    hipLaunchKernelGGL(k_conv8, dim3(NPIX / 8), dim3(192), 0, stream,
                       xin, cw, cb, xg);
    hipLaunchKernelGGL(k_xdbl, dim3(NBK * 16), dim3(256), 0, stream,
                       xg, xpw, dtr, Bm, Cm);
    hipLaunchKernelGGL(k_scan1, dim3(NBK * NCH), dim3(192), 0, stream,
                       dtr, xg, Bm, Alog, dtw, dtb, Pbuf, QH);
    hipLaunchKernelGGL(k_scan2, dim3(NSTATES / 256), dim3(256), 0, stream,
                       Pbuf, QH);
    hipLaunchKernelGGL(k_scan3, dim3(NBK * NCH), dim3(192), 0, stream,
                       dtr, xg, Bm, Cm, Alog, dtw, dtb, Ds, QH, yout);
    hipLaunchKernelGGL(k_lnout, dim3(NPIX / 32), dim3(256), 0, stream,
                       yout, zbuf, lng, lnb, WtOut, out);
}

// Round 6
// 203.650 us; speedup vs baseline: 1.4887x; 1.0003x over previous
//
#include <hip/hip_runtime.h>
#include <math.h>

// SS2D (VMamba v2) forward — MI355X gfx950, fp32 throughout.
//
// Pipeline (7 dispatches):
//  k_setup  : W_in -> WtIn (96x384), W_out -> WtOut (192x96)
//  k_inproj : xz = x @ W_in^T ; xin = xz[:,:192], z = silu(xz[:,192:])
//  k_conv8  : depthwise 3x3 SAME + bias + silu -> xg (scan order)
//  k_scan1g : per 16-step chunk: x_dbl GEMM into LDS (rows<22) + local scan -> P,Q
//  k_scan2  : prefix over 64 chunks per state (in place, float2 ILP)
//  k_scan3g : x_dbl GEMM recompute (38 rows) + replay with true h_in -> yout
//  k_lnout  : merge + LayerNorm(192) + gate(z) + out GEMM (fused)

#define DINNER 192
#define NSTATE 16
#define KDIR 4
#define BATCH 4
#define NPIX (BATCH * 64 * 64)          // 16384
#define LP 1024
#define NCH 64                          // scan chunks
#define CHUNK 16                        // LP / NCH
#define NBK (BATCH * KDIR)              // 16
#define NSTATES (NBK * DINNER * NSTATE) // 49152
#define USTRIDE 196                     // sU row stride (floats)

__device__ __forceinline__ float silu_f(float x) {
    return x / (1.0f + __expf(-x));
}
__device__ __forceinline__ float softplus_f(float a) {
    return (a > 20.0f) ? a : __logf(1.0f + __expf(a));
}

__global__ __launch_bounds__(256) void k_setup(
        const float* __restrict__ W_in, const float* __restrict__ W_out,
        float* __restrict__ WtIn, float* __restrict__ WtOut) {
    int i = blockIdx.x * 256 + threadIdx.x;
    if (i < 96 * 384) {               // WtIn[c*384+e] = W_in[e*96+c]
        int c = i / 384, e = i % 384;
        WtIn[i] = W_in[e * 96 + c];
    }
    if (i < 192 * 96) {               // WtOut[d*96+o] = W_out[o*192+d]
        int d = i / 96, o = i % 96;
        WtOut[i] = W_out[o * 192 + d];
    }
}

// 32 pixels/block; thread (pi=t>>6, ei=t&63) -> acc over 6 e-groups x 8 pixels
__global__ __launch_bounds__(256) void k_inproj(
        const float* __restrict__ x, const float* __restrict__ WtIn,
        float* __restrict__ xin, float* __restrict__ z) {
    __shared__ float xs[32 * 96];
    int p0 = blockIdx.x * 32;
    int t = threadIdx.x;
    for (int i = t; i < 32 * 96; i += 256) xs[i] = x[p0 * 96 + i];
    __syncthreads();
    int ei = t & 63;
    int pi = t >> 6;
    float acc[6][8];
    #pragma unroll
    for (int j = 0; j < 6; ++j)
        #pragma unroll
        for (int pp = 0; pp < 8; ++pp) acc[j][pp] = 0.0f;
    for (int c = 0; c < 96; ++c) {
        float wv[6];
        #pragma unroll
        for (int j = 0; j < 6; ++j) wv[j] = WtIn[c * 384 + j * 64 + ei];
        #pragma unroll
        for (int pp = 0; pp < 8; ++pp) {
            float xv = xs[(pi * 8 + pp) * 96 + c];
            #pragma unroll
            for (int j = 0; j < 6; ++j) acc[j][pp] = fmaf(wv[j], xv, acc[j][pp]);
        }
    }
    #pragma unroll
    for (int j = 0; j < 6; ++j) {
        int e = j * 64 + ei;
        #pragma unroll
        for (int pp = 0; pp < 8; ++pp) {
            int p = p0 + pi * 8 + pp;
            if (e < 192) xin[p * 192 + e] = acc[j][pp];
            else         z[p * 192 + (e - 192)] = silu_f(acc[j][pp]);
        }
    }
}

// depthwise 3x3, 8 consecutive pixels of one row per block; sliding-window loads.
// Output in scan order xg[(bk*1024+l)*192+d].
__global__ __launch_bounds__(192) void k_conv8(
        const float* __restrict__ xin, const float* __restrict__ cw,
        const float* __restrict__ cb, float* __restrict__ xg) {
    int blk = blockIdx.x;             // 2048 = 4 b * 64 h * 8 wchunks
    int b = blk >> 9;
    int rem = blk & 511;
    int h = rem >> 3;
    int w0 = (rem & 7) * 8;
    int d = threadIdx.x;
    float wr[3][3];
    #pragma unroll
    for (int i = 0; i < 3; ++i)
        #pragma unroll
        for (int j = 0; j < 3; ++j) wr[i][j] = cw[d * 9 + i * 3 + j];
    float bias = cb[d];
    float acc[8];
    #pragma unroll
    for (int o = 0; o < 8; ++o) acc[o] = bias;
    #pragma unroll
    for (int jj = 0; jj < 10; ++jj) {
        int ww = w0 + jj - 1;
        float r0 = 0.0f, r1 = 0.0f, r2 = 0.0f;
        if ((unsigned)ww < 64u) {
            const float* base = xin + ((size_t)b * 4096 + h * 64 + ww) * 192 + d;
            if (h > 0)  r0 = base[-64 * 192];
            r1 = base[0];
            if (h < 63) r2 = base[64 * 192];
        }
        #pragma unroll
        for (int dd2 = 0; dd2 < 3; ++dd2) {
            int o = jj - 2 + dd2;
            int cj = 2 - dd2;
            if (o >= 0 && o < 8) {
                acc[o] = fmaf(r0, wr[0][cj], acc[o]);
                acc[o] = fmaf(r1, wr[1][cj], acc[o]);
                acc[o] = fmaf(r2, wr[2][cj], acc[o]);
            }
        }
    }
    #pragma unroll
    for (int o = 0; o < 8; ++o) {
        int w = w0 + o;
        int kq = (h & 1) ? ((w & 1) ? 3 : 1) : ((w & 1) ? 2 : 0);
        int l = (kq & 1) ? ((w >> 1) * 32 + (h >> 1))
                         : ((h >> 1) * 32 + (w >> 1));
        xg[((size_t)(b * 4 + kq) * 1024 + l) * 192 + d] = silu_f(acc[o]);
    }
}

// Pass 1 (fused x_dbl): stage u tile, GEMM rows 0..21 (dtr+B) into LDS, scan.
__global__ __launch_bounds__(192) void k_scan1g(
        const float* __restrict__ xg, const float* __restrict__ xpw,
        const float* __restrict__ A_logs, const float* __restrict__ dtw,
        const float* __restrict__ dtb,
        float* __restrict__ Pbuf, float* __restrict__ Qbuf) {
    __shared__ float sU[CHUNK * USTRIDE];
    __shared__ float sB[CHUNK * 16];
    __shared__ float sR[CHUNK * 8];
    int bk = blockIdx.x >> 6;
    int ch = blockIdx.x & 63;
    int k = bk & 3;
    int t = threadIdx.x;
    int d = t;
    int lbase = bk * 1024 + ch * CHUNK;
    const float4* usrc = (const float4*)(xg + (size_t)lbase * 192);
    for (int i = t; i < CHUNK * 48; i += 192) {
        int l = i / 48, c4 = i - l * 48;
        *(float4*)&sU[l * USTRIDE + c4 * 4] = usrc[i];
    }
    float A[16];
    #pragma unroll
    for (int n = 0; n < 16; ++n) A[n] = -__expf(A_logs[(k * 192 + d) * 16 + n]);
    float wp[6];
    #pragma unroll
    for (int q = 0; q < 6; ++q) wp[q] = dtw[(k * 192 + d) * 6 + q];
    float bias = dtb[k * 192 + d];
    __syncthreads();
    // x_dbl GEMM rows c = cgp, cgp+12 (c < 22 only)
    {
        int l = t & 15, cgp = t >> 4;       // 16 l x 12 c-groups
        float acc0 = 0.0f, acc1 = 0.0f;
        const float* wb = xpw + (size_t)k * 38 * 192;
        int c1 = cgp + 12;
        int c1r = (c1 < 22) ? c1 : cgp;     // clamp row for safe read
        for (int qv = 0; qv < 48; ++qv) {
            float4 xv = *(const float4*)&sU[l * USTRIDE + qv * 4];
            float4 w0 = *(const float4*)&wb[(size_t)cgp * 192 + qv * 4];
            float4 w1 = *(const float4*)&wb[(size_t)c1r * 192 + qv * 4];
            acc0 = fmaf(xv.x, w0.x, fmaf(xv.y, w0.y, fmaf(xv.z, w0.z, fmaf(xv.w, w0.w, acc0))));
            acc1 = fmaf(xv.x, w1.x, fmaf(xv.y, w1.y, fmaf(xv.z, w1.z, fmaf(xv.w, w1.w, acc1))));
        }
        if (cgp < 6) sR[l * 8 + cgp] = acc0;
        else         sB[l * 16 + (cgp - 6)] = acc0;
        if (c1 < 22) sB[l * 16 + (c1 - 6)] = acc1;
    }
    __syncthreads();
    float h[16], P[16];
    #pragma unroll
    for (int n = 0; n < 16; ++n) { h[n] = 0.0f; P[n] = 1.0f; }
    for (int l = 0; l < CHUNK; ++l) {
        float a = bias;
        #pragma unroll
        for (int q = 0; q < 6; ++q) a = fmaf(wp[q], sR[l * 8 + q], a);
        float dlt = softplus_f(a);
        float du = dlt * sU[l * USTRIDE + d];
        #pragma unroll
        for (int n = 0; n < 16; ++n) {
            float e = __expf(dlt * A[n]);
            h[n] = fmaf(e, h[n], du * sB[l * 16 + n]);
            P[n] *= e;
        }
    }
    size_t base = (size_t)ch * NSTATES + bk * (192 * 16);
    #pragma unroll
    for (int n = 0; n < 16; ++n) {
        Pbuf[base + n * 192 + d] = P[n];
        Qbuf[base + n * 192 + d] = h[n];
    }
}

// Pass 2: prefix over chunks, 2 states per thread (float2 ILP), in place.
__global__ __launch_bounds__(256) void k_scan2(
        const float* __restrict__ Pbuf, float* QH) {
    int s2 = blockIdx.x * 256 + threadIdx.x;   // state pair index
    float2 h = make_float2(0.0f, 0.0f);
    const float2* P2 = (const float2*)Pbuf;
    float2* Q2 = (float2*)QH;
    #pragma unroll 4
    for (int c = 0; c < NCH; ++c) {
        size_t idx = (size_t)c * (NSTATES / 2) + s2;
        float2 q = Q2[idx];
        float2 p = P2[idx];
        Q2[idx] = h;
        h.x = fmaf(p.x, h.x, q.x);
        h.y = fmaf(p.y, h.y, q.y);
    }
}

// Pass 3 (fused x_dbl): GEMM recompute (all 38 rows), replay with true h_in.
__global__ __launch_bounds__(192) void k_scan3g(
        const float* __restrict__ xg, const float* __restrict__ xpw,
        const float* __restrict__ A_logs, const float* __restrict__ dtw,
        const float* __restrict__ dtb, const float* __restrict__ Ds,
        const float* __restrict__ QH, float* __restrict__ yout) {
    __shared__ float sU[CHUNK * USTRIDE];
    __shared__ float sB[CHUNK * 16];
    __shared__ float sC[CHUNK * 16];
    __shared__ float sR[CHUNK * 8];
    int bk = blockIdx.x >> 6;
    int ch = blockIdx.x & 63;
    int k = bk & 3;
    int t = threadIdx.x;
    int d = t;
    int lbase = bk * 1024 + ch * CHUNK;
    const float4* usrc = (const float4*)(xg + (size_t)lbase * 192);
    for (int i = t; i < CHUNK * 48; i += 192) {
        int l = i / 48, c4 = i - l * 48;
        *(float4*)&sU[l * USTRIDE + c4 * 4] = usrc[i];
    }
    float A[16];
    #pragma unroll
    for (int n = 0; n < 16; ++n) A[n] = -__expf(A_logs[(k * 192 + d) * 16 + n]);
    float wp[6];
    #pragma unroll
    for (int q = 0; q < 6; ++q) wp[q] = dtw[(k * 192 + d) * 6 + q];
    float bias = dtb[k * 192 + d];
    float Dp = Ds[k * 192 + d];
    __syncthreads();
    // x_dbl GEMM: 38 rows via c in {cgp, cgp+12, cgp+24, cgp+36 (cgp<2)}
    {
        int l = t & 15, cgp = t >> 4;
        float acc[4] = {0.f, 0.f, 0.f, 0.f};
        int c3 = (cgp < 2) ? (cgp + 36) : cgp;
        const float* wb = xpw + (size_t)k * 38 * 192;
        for (int qv = 0; qv < 48; ++qv) {
            float4 xv = *(const float4*)&sU[l * USTRIDE + qv * 4];
            float4 w0 = *(const float4*)&wb[(cgp +  0) * 192 + qv * 4];
            float4 w1 = *(const float4*)&wb[(cgp + 12) * 192 + qv * 4];
            float4 w2 = *(const float4*)&wb[(cgp + 24) * 192 + qv * 4];
            float4 w3 = *(const float4*)&wb[(size_t)c3 * 192 + qv * 4];
            acc[0] = fmaf(xv.x, w0.x, fmaf(xv.y, w0.y, fmaf(xv.z, w0.z, fmaf(xv.w, w0.w, acc[0]))));
            acc[1] = fmaf(xv.x, w1.x, fmaf(xv.y, w1.y, fmaf(xv.z, w1.z, fmaf(xv.w, w1.w, acc[1]))));
            acc[2] = fmaf(xv.x, w2.x, fmaf(xv.y, w2.y, fmaf(xv.z, w2.z, fmaf(xv.w, w2.w, acc[2]))));
            acc[3] = fmaf(xv.x, w3.x, fmaf(xv.y, w3.y, fmaf(xv.z, w3.z, fmaf(xv.w, w3.w, acc[3]))));
        }
        #pragma unroll
        for (int j = 0; j < 4; ++j) {
            int c = cgp + 12 * j;
            if (j == 3) { if (cgp >= 2) break; c = cgp + 36; }
            float v = acc[j];
            if (c < 6)       sR[l * 8 + c] = v;
            else if (c < 22) sB[l * 16 + (c - 6)] = v;
            else             sC[l * 16 + (c - 22)] = v;
        }
    }
    float h[16];
    size_t base = (size_t)ch * NSTATES + bk * (192 * 16);
    #pragma unroll
    for (int n = 0; n < 16; ++n) h[n] = QH[base + n * 192 + d];
    __syncthreads();
    for (int l = 0; l < CHUNK; ++l) {
        float a = bias;
        #pragma unroll
        for (int q = 0; q < 6; ++q) a = fmaf(wp[q], sR[l * 8 + q], a);
        float dlt = softplus_f(a);
        float u = sU[l * USTRIDE + d];
        float du = dlt * u;
        float y = 0.0f;
        #pragma unroll
        for (int n = 0; n < 16; ++n) {
            float e = __expf(dlt * A[n]);
            h[n] = fmaf(e, h[n], du * sB[l * 16 + n]);
            y = fmaf(h[n], sC[l * 16 + n], y);
        }
        yout[(size_t)(lbase + l) * 192 + d] = fmaf(u, Dp, y);
    }
}

// Fused: merge + LayerNorm(192) + gate(z) + out GEMM. 32 pixels/block.
__global__ __launch_bounds__(256) void k_lnout(
        const float* __restrict__ yout, const float* __restrict__ z,
        const float* __restrict__ lng, const float* __restrict__ lnb,
        const float* __restrict__ WoT, float* __restrict__ out) {
    __shared__ float sg[32 * 196];     // stride 196 floats (784B, 16B-aligned)
    int p0 = blockIdx.x * 32;
    int t = threadIdx.x;
    int p = t >> 3;                    // pixel 0..31
    int sub = t & 7;                   // 8 threads per pixel, 24 channels each
    int gp = p0 + p;
    int b = gp >> 12;
    int hw = gp & 4095;
    int h = hw >> 6, w = hw & 63;
    int kq = (h & 1) ? ((w & 1) ? 3 : 1) : ((w & 1) ? 2 : 0);
    int l = (kq & 1) ? ((w >> 1) * 32 + (h >> 1))
                     : ((h >> 1) * 32 + (w >> 1));
    const float* yrow = yout + ((size_t)(b * 4 + kq) * 1024 + l) * 192 + sub * 24;
    float4 yv[6];
    float s = 0.0f, s2 = 0.0f;
    #pragma unroll
    for (int j = 0; j < 6; ++j) {
        float4 v = *(const float4*)(yrow + j * 4);
        yv[j] = v;
        s += v.x + v.y + v.z + v.w;
        s2 += v.x * v.x + v.y * v.y + v.z * v.z + v.w * v.w;
    }
    #pragma unroll
    for (int off = 1; off < 8; off <<= 1) {
        s  += __shfl_xor(s, off, 8);
        s2 += __shfl_xor(s2, off, 8);
    }
    float mu = s * (1.0f / 192.0f);
    float var = s2 * (1.0f / 192.0f) - mu * mu;
    float rstd = rsqrtf(var + 1e-5f);
    const float* zrow = z + (size_t)gp * 192 + sub * 24;
    float* grow = sg + p * 196 + sub * 24;
    #pragma unroll
    for (int j = 0; j < 6; ++j) {
        float4 zv = *(const float4*)(zrow + j * 4);
        float4 gv = *(const float4*)(lng + sub * 24 + j * 4);
        float4 bv = *(const float4*)(lnb + sub * 24 + j * 4);
        float4 o;
        o.x = ((yv[j].x - mu) * rstd * gv.x + bv.x) * zv.x;
        o.y = ((yv[j].y - mu) * rstd * gv.y + bv.y) * zv.y;
        o.z = ((yv[j].z - mu) * rstd * gv.z + bv.z) * zv.z;
        o.w = ((yv[j].w - mu) * rstd * gv.w + bv.w) * zv.w;
        *(float4*)(grow + j * 4) = o;
    }
    __syncthreads();
    int oi = t & 31, wi = t >> 5;
    float acc[4][3];
    #pragma unroll
    for (int pp = 0; pp < 4; ++pp)
        #pragma unroll
        for (int j = 0; j < 3; ++j) acc[pp][j] = 0.0f;
    for (int dd = 0; dd < 192; dd += 4) {
        float4 q0 = *(const float4*)&sg[(wi * 4 + 0) * 196 + dd];
        float4 q1 = *(const float4*)&sg[(wi * 4 + 1) * 196 + dd];
        float4 q2 = *(const float4*)&sg[(wi * 4 + 2) * 196 + dd];
        float4 q3 = *(const float4*)&sg[(wi * 4 + 3) * 196 + dd];
        #pragma unroll
        for (int r = 0; r < 4; ++r) {
            float w0 = WoT[(dd + r) * 96 + oi];
            float w1 = WoT[(dd + r) * 96 + oi + 32];
            float w2 = WoT[(dd + r) * 96 + oi + 64];
            float e0 = (r == 0) ? q0.x : (r == 1) ? q0.y : (r == 2) ? q0.z : q0.w;
            float e1 = (r == 0) ? q1.x : (r == 1) ? q1.y : (r == 2) ? q1.z : q1.w;
            float e2 = (r == 0) ? q2.x : (r == 1) ? q2.y : (r == 2) ? q2.z : q2.w;
            float e3 = (r == 0) ? q3.x : (r == 1) ? q3.y : (r == 2) ? q3.z : q3.w;
            acc[0][0] = fmaf(e0, w0, acc[0][0]);
            acc[0][1] = fmaf(e0, w1, acc[0][1]);
            acc[0][2] = fmaf(e0, w2, acc[0][2]);
            acc[1][0] = fmaf(e1, w0, acc[1][0]);
            acc[1][1] = fmaf(e1, w1, acc[1][1]);
            acc[1][2] = fmaf(e1, w2, acc[1][2]);
            acc[2][0] = fmaf(e2, w0, acc[2][0]);
            acc[2][1] = fmaf(e2, w1, acc[2][1]);
            acc[2][2] = fmaf(e2, w2, acc[2][2]);
            acc[3][0] = fmaf(e3, w0, acc[3][0]);
            acc[3][1] = fmaf(e3, w1, acc[3][1]);
            acc[3][2] = fmaf(e3, w2, acc[3][2]);
        }
    }
    #pragma unroll
    for (int pp = 0; pp < 4; ++pp)
        #pragma unroll
        for (int j = 0; j < 3; ++j)
            out[(size_t)(p0 + wi * 4 + pp) * 96 + oi + 32 * j] = acc[pp][j];
}

extern "C" void kernel_launch(void* const* d_in, const int* in_sizes, int n_in,
                              void* d_out, int out_size, void* d_ws, size_t ws_size,
                              hipStream_t stream) {
    const float* x    = (const float*)d_in[0];
    const float* W_in = (const float*)d_in[1];
    const float* cw   = (const float*)d_in[2];
    const float* cb   = (const float*)d_in[3];
    const float* xpw  = (const float*)d_in[4];
    const float* dtw  = (const float*)d_in[5];
    const float* dtb  = (const float*)d_in[6];
    const float* Alog = (const float*)d_in[7];
    const float* Ds   = (const float*)d_in[8];
    const float* lng  = (const float*)d_in[9];
    const float* lnb  = (const float*)d_in[10];
    const float* Wout = (const float*)d_in[11];
    float* out = (float*)d_out;

    float* ws = (float*)d_ws;
    size_t off = 0;
    float* WtIn  = ws + off; off += 96 * 384;
    float* WtOut = ws + off; off += 192 * 96;
    float* xin   = ws + off; off += (size_t)NPIX * 192;
    float* zbuf  = ws + off; off += (size_t)NPIX * 192;
    float* xg    = ws + off; off += (size_t)NPIX * 192;
    float* Pbuf  = ws + off; off += (size_t)NCH * NSTATES;
    float* QH    = ws + off; off += (size_t)NCH * NSTATES;
    float* yout  = ws + off; off += (size_t)NBK * LP * 192;

    hipLaunchKernelGGL(k_setup, dim3(144), dim3(256), 0, stream,
                       W_in, Wout, WtIn, WtOut);
    hipLaunchKernelGGL(k_inproj, dim3(NPIX / 32), dim3(256), 0, stream,
                       x, WtIn, xin, zbuf);
    hipLaunchKernelGGL(k_conv8, dim3(NPIX / 8), dim3(192), 0, stream,
                       xin, cw, cb, xg);
    hipLaunchKernelGGL(k_scan1g, dim3(NBK * NCH), dim3(192), 0, stream,
                       xg, xpw, Alog, dtw, dtb, Pbuf, QH);
    hipLaunchKernelGGL(k_scan2, dim3(NSTATES / 512), dim3(256), 0, stream,
                       Pbuf, QH);
    hipLaunchKernelGGL(k_scan3g, dim3(NBK * NCH), dim3(192), 0, stream,
                       xg, xpw, Alog, dtw, dtb, Ds, QH, yout);
    hipLaunchKernelGGL(k_lnout, dim3(NPIX / 32), dim3(256), 0, stream,
                       yout, zbuf, lng, lnb, WtOut, out);
}

// Round 8
// 195.822 us; speedup vs baseline: 1.5482x; 1.0400x over previous
//
#include <hip/hip_runtime.h>
#include <math.h>

// SS2D (VMamba v2) forward — MI355X gfx950. fp32 core; bf16 MFMA out-proj only.
//
// Pipeline (7 dispatches):
//  k_setup  : W_in -> WtIn (96x384 transpose), W_out -> bf16 (row-major cast)
//  k_inproj : xz = x @ W_in^T (fp32 VALU); xin = xz[:,:192], z = silu(rest)
//  k_conv8  : depthwise 3x3 SAME + bias + silu -> xg (scan order)
//  k_scan1g : per 16-step chunk: x_dbl GEMM into LDS (rows<22) + local scan
//  k_scan2  : prefix over 64 chunks per state (float2 ILP, in place)
//  k_scan3g : x_dbl GEMM recompute (38 rows) + replay with true h_in
//  k_lnout  : merge + LayerNorm + gate -> bf16 LDS -> MFMA out GEMM

#define DINNER 192
#define NSTATE 16
#define KDIR 4
#define BATCH 4
#define NPIX (BATCH * 64 * 64)          // 16384
#define LP 1024
#define NCH 64                          // scan chunks
#define CHUNK 16                        // LP / NCH
#define NBK (BATCH * KDIR)              // 16
#define NSTATES (NBK * DINNER * NSTATE) // 49152
#define USTRIDE 196                     // sU row stride (floats)
#define GSTRIDE 200                     // lnout bf16 g LDS stride (shorts)

typedef __attribute__((ext_vector_type(8))) short short8;
typedef __attribute__((ext_vector_type(4))) short short4v;
typedef __attribute__((ext_vector_type(4))) float f32x4;

__device__ __forceinline__ float silu_f(float x) {
    return x / (1.0f + __expf(-x));
}
__device__ __forceinline__ float softplus_f(float a) {
    return (a > 20.0f) ? a : __logf(1.0f + __expf(a));
}
__device__ __forceinline__ unsigned short f2bf(float f) {
    unsigned u = __float_as_uint(f);
    unsigned r = (u + 0x7FFFu + ((u >> 16) & 1u)) >> 16;
    return (unsigned short)r;
}

// WtIn transpose (for fp32 inproj) + W_out bf16 cast (row-major, for MFMA).
__global__ __launch_bounds__(256) void k_setup(
        const float* __restrict__ W_in, const float* __restrict__ W_out,
        float* __restrict__ WtIn, unsigned short* __restrict__ Wo_bf) {
    int i = blockIdx.x * 256 + threadIdx.x;
    if (i < 96 * 384) {               // WtIn[c*384+e] = W_in[e*96+c]
        int c = i / 384, e = i % 384;
        WtIn[i] = W_in[e * 96 + c];
    }
    if (i < 96 * DINNER) Wo_bf[i] = f2bf(W_out[i]);
}

// 32 pixels/block; thread (pi=t>>6, ei=t&63) -> acc over 6 e-groups x 8 pixels
__global__ __launch_bounds__(256) void k_inproj(
        const float* __restrict__ x, const float* __restrict__ WtIn,
        float* __restrict__ xin, float* __restrict__ z) {
    __shared__ float xs[32 * 96];
    int p0 = blockIdx.x * 32;
    int t = threadIdx.x;
    for (int i = t; i < 32 * 96; i += 256) xs[i] = x[p0 * 96 + i];
    __syncthreads();
    int ei = t & 63;
    int pi = t >> 6;
    float acc[6][8];
    #pragma unroll
    for (int j = 0; j < 6; ++j)
        #pragma unroll
        for (int pp = 0; pp < 8; ++pp) acc[j][pp] = 0.0f;
    for (int c = 0; c < 96; ++c) {
        float wv[6];
        #pragma unroll
        for (int j = 0; j < 6; ++j) wv[j] = WtIn[c * 384 + j * 64 + ei];
        #pragma unroll
        for (int pp = 0; pp < 8; ++pp) {
            float xv = xs[(pi * 8 + pp) * 96 + c];
            #pragma unroll
            for (int j = 0; j < 6; ++j) acc[j][pp] = fmaf(wv[j], xv, acc[j][pp]);
        }
    }
    #pragma unroll
    for (int j = 0; j < 6; ++j) {
        int e = j * 64 + ei;
        #pragma unroll
        for (int pp = 0; pp < 8; ++pp) {
            int p = p0 + pi * 8 + pp;
            if (e < 192) xin[p * 192 + e] = acc[j][pp];
            else         z[p * 192 + (e - 192)] = silu_f(acc[j][pp]);
        }
    }
}

// depthwise 3x3, 8 consecutive pixels of one row per block; sliding-window loads.
// Output in scan order xg[(bk*1024+l)*192+d].
__global__ __launch_bounds__(192) void k_conv8(
        const float* __restrict__ xin, const float* __restrict__ cw,
        const float* __restrict__ cb, float* __restrict__ xg) {
    int blk = blockIdx.x;             // 2048 = 4 b * 64 h * 8 wchunks
    int b = blk >> 9;
    int rem = blk & 511;
    int h = rem >> 3;
    int w0 = (rem & 7) * 8;
    int d = threadIdx.x;
    float wr[3][3];
    #pragma unroll
    for (int i = 0; i < 3; ++i)
        #pragma unroll
        for (int j = 0; j < 3; ++j) wr[i][j] = cw[d * 9 + i * 3 + j];
    float bias = cb[d];
    float acc[8];
    #pragma unroll
    for (int o = 0; o < 8; ++o) acc[o] = bias;
    #pragma unroll
    for (int jj = 0; jj < 10; ++jj) {
        int ww = w0 + jj - 1;
        float r0 = 0.0f, r1 = 0.0f, r2 = 0.0f;
        if ((unsigned)ww < 64u) {
            const float* base = xin + ((size_t)b * 4096 + h * 64 + ww) * 192 + d;
            if (h > 0)  r0 = base[-64 * 192];
            r1 = base[0];
            if (h < 63) r2 = base[64 * 192];
        }
        #pragma unroll
        for (int dd2 = 0; dd2 < 3; ++dd2) {
            int o = jj - 2 + dd2;
            int cj = 2 - dd2;
            if (o >= 0 && o < 8) {
                acc[o] = fmaf(r0, wr[0][cj], acc[o]);
                acc[o] = fmaf(r1, wr[1][cj], acc[o]);
                acc[o] = fmaf(r2, wr[2][cj], acc[o]);
            }
        }
    }
    #pragma unroll
    for (int o = 0; o < 8; ++o) {
        int w = w0 + o;
        int kq = (h & 1) ? ((w & 1) ? 3 : 1) : ((w & 1) ? 2 : 0);
        int l = (kq & 1) ? ((w >> 1) * 32 + (h >> 1))
                         : ((h >> 1) * 32 + (w >> 1));
        xg[((size_t)(b * 4 + kq) * 1024 + l) * 192 + d] = silu_f(acc[o]);
    }
}

// Pass 1 (fused x_dbl): stage u tile, GEMM rows 0..21 (dtr+B) into LDS, scan.
__global__ __launch_bounds__(192) void k_scan1g(
        const float* __restrict__ xg, const float* __restrict__ xpw,
        const float* __restrict__ A_logs, const float* __restrict__ dtw,
        const float* __restrict__ dtb,
        float* __restrict__ Pbuf, float* __restrict__ Qbuf) {
    __shared__ float sU[CHUNK * USTRIDE];
    __shared__ float sB[CHUNK * 16];
    __shared__ float sR[CHUNK * 8];
    int bk = blockIdx.x >> 6;
    int ch = blockIdx.x & 63;
    int k = bk & 3;
    int t = threadIdx.x;
    int d = t;
    int lbase = bk * 1024 + ch * CHUNK;
    const float4* usrc = (const float4*)(xg + (size_t)lbase * 192);
    for (int i = t; i < CHUNK * 48; i += 192) {
        int l = i / 48, c4 = i - l * 48;
        *(float4*)&sU[l * USTRIDE + c4 * 4] = usrc[i];
    }
    float A[16];
    #pragma unroll
    for (int n = 0; n < 16; ++n) A[n] = -__expf(A_logs[(k * 192 + d) * 16 + n]);
    float wp[6];
    #pragma unroll
    for (int q = 0; q < 6; ++q) wp[q] = dtw[(k * 192 + d) * 6 + q];
    float bias = dtb[k * 192 + d];
    __syncthreads();
    {
        int l = t & 15, cgp = t >> 4;       // 16 l x 12 c-groups
        float acc0 = 0.0f, acc1 = 0.0f;
        const float* wb = xpw + (size_t)k * 38 * 192;
        int c1 = cgp + 12;
        int c1r = (c1 < 22) ? c1 : cgp;
        for (int qv = 0; qv < 48; ++qv) {
            float4 xv = *(const float4*)&sU[l * USTRIDE + qv * 4];
            float4 w0 = *(const float4*)&wb[(size_t)cgp * 192 + qv * 4];
            float4 w1 = *(const float4*)&wb[(size_t)c1r * 192 + qv * 4];
            acc0 = fmaf(xv.x, w0.x, fmaf(xv.y, w0.y, fmaf(xv.z, w0.z, fmaf(xv.w, w0.w, acc0))));
            acc1 = fmaf(xv.x, w1.x, fmaf(xv.y, w1.y, fmaf(xv.z, w1.z, fmaf(xv.w, w1.w, acc1))));
        }
        if (cgp < 6) sR[l * 8 + cgp] = acc0;
        else         sB[l * 16 + (cgp - 6)] = acc0;
        if (c1 < 22) sB[l * 16 + (c1 - 6)] = acc1;
    }
    __syncthreads();
    float h[16], P[16];
    #pragma unroll
    for (int n = 0; n < 16; ++n) { h[n] = 0.0f; P[n] = 1.0f; }
    for (int l = 0; l < CHUNK; ++l) {
        float a = bias;
        #pragma unroll
        for (int q = 0; q < 6; ++q) a = fmaf(wp[q], sR[l * 8 + q], a);
        float dlt = softplus_f(a);
        float du = dlt * sU[l * USTRIDE + d];
        #pragma unroll
        for (int n = 0; n < 16; ++n) {
            float e = __expf(dlt * A[n]);
            h[n] = fmaf(e, h[n], du * sB[l * 16 + n]);
            P[n] *= e;
        }
    }
    size_t base = (size_t)ch * NSTATES + bk * (192 * 16);
    #pragma unroll
    for (int n = 0; n < 16; ++n) {
        Pbuf[base + n * 192 + d] = P[n];
        Qbuf[base + n * 192 + d] = h[n];
    }
}

// Pass 2: prefix over chunks, 2 states per thread (float2 ILP), in place.
__global__ __launch_bounds__(256) void k_scan2(
        const float* __restrict__ Pbuf, float* QH) {
    int s2 = blockIdx.x * 256 + threadIdx.x;   // state pair index
    float2 h = make_float2(0.0f, 0.0f);
    const float2* P2 = (const float2*)Pbuf;
    float2* Q2 = (float2*)QH;
    #pragma unroll 4
    for (int c = 0; c < NCH; ++c) {
        size_t idx = (size_t)c * (NSTATES / 2) + s2;
        float2 q = Q2[idx];
        float2 p = P2[idx];
        Q2[idx] = h;
        h.x = fmaf(p.x, h.x, q.x);
        h.y = fmaf(p.y, h.y, q.y);
    }
}

// Pass 3 (fused x_dbl): GEMM recompute (all 38 rows), replay with true h_in.
__global__ __launch_bounds__(192) void k_scan3g(
        const float* __restrict__ xg, const float* __restrict__ xpw,
        const float* __restrict__ A_logs, const float* __restrict__ dtw,
        const float* __restrict__ dtb, const float* __restrict__ Ds,
        const float* __restrict__ QH, float* __restrict__ yout) {
    __shared__ float sU[CHUNK * USTRIDE];
    __shared__ float sB[CHUNK * 16];
    __shared__ float sC[CHUNK * 16];
    __shared__ float sR[CHUNK * 8];
    int bk = blockIdx.x >> 6;
    int ch = blockIdx.x & 63;
    int k = bk & 3;
    int t = threadIdx.x;
    int d = t;
    int lbase = bk * 1024 + ch * CHUNK;
    const float4* usrc = (const float4*)(xg + (size_t)lbase * 192);
    for (int i = t; i < CHUNK * 48; i += 192) {
        int l = i / 48, c4 = i - l * 48;
        *(float4*)&sU[l * USTRIDE + c4 * 4] = usrc[i];
    }
    float A[16];
    #pragma unroll
    for (int n = 0; n < 16; ++n) A[n] = -__expf(A_logs[(k * 192 + d) * 16 + n]);
    float wp[6];
    #pragma unroll
    for (int q = 0; q < 6; ++q) wp[q] = dtw[(k * 192 + d) * 6 + q];
    float bias = dtb[k * 192 + d];
    float Dp = Ds[k * 192 + d];
    __syncthreads();
    {
        int l = t & 15, cgp = t >> 4;
        float acc[4] = {0.f, 0.f, 0.f, 0.f};
        int c3 = (cgp < 2) ? (cgp + 36) : cgp;
        const float* wb = xpw + (size_t)k * 38 * 192;
        for (int qv = 0; qv < 48; ++qv) {
            float4 xv = *(const float4*)&sU[l * USTRIDE + qv * 4];
            float4 w0 = *(const float4*)&wb[(cgp +  0) * 192 + qv * 4];
            float4 w1 = *(const float4*)&wb[(cgp + 12) * 192 + qv * 4];
            float4 w2 = *(const float4*)&wb[(cgp + 24) * 192 + qv * 4];
            float4 w3 = *(const float4*)&wb[(size_t)c3 * 192 + qv * 4];
            acc[0] = fmaf(xv.x, w0.x, fmaf(xv.y, w0.y, fmaf(xv.z, w0.z, fmaf(xv.w, w0.w, acc[0]))));
            acc[1] = fmaf(xv.x, w1.x, fmaf(xv.y, w1.y, fmaf(xv.z, w1.z, fmaf(xv.w, w1.w, acc[1]))));
            acc[2] = fmaf(xv.x, w2.x, fmaf(xv.y, w2.y, fmaf(xv.z, w2.z, fmaf(xv.w, w2.w, acc[2]))));
            acc[3] = fmaf(xv.x, w3.x, fmaf(xv.y, w3.y, fmaf(xv.z, w3.z, fmaf(xv.w, w3.w, acc[3]))));
        }
        #pragma unroll
        for (int j = 0; j < 4; ++j) {
            int c = cgp + 12 * j;
            if (j == 3) { if (cgp >= 2) break; c = cgp + 36; }
            float v = acc[j];
            if (c < 6)       sR[l * 8 + c] = v;
            else if (c < 22) sB[l * 16 + (c - 6)] = v;
            else             sC[l * 16 + (c - 22)] = v;
        }
    }
    float h[16];
    size_t base = (size_t)ch * NSTATES + bk * (192 * 16);
    #pragma unroll
    for (int n = 0; n < 16; ++n) h[n] = QH[base + n * 192 + d];
    __syncthreads();
    for (int l = 0; l < CHUNK; ++l) {
        float a = bias;
        #pragma unroll
        for (int q = 0; q < 6; ++q) a = fmaf(wp[q], sR[l * 8 + q], a);
        float dlt = softplus_f(a);
        float u = sU[l * USTRIDE + d];
        float du = dlt * u;
        float y = 0.0f;
        #pragma unroll
        for (int n = 0; n < 16; ++n) {
            float e = __expf(dlt * A[n]);
            h[n] = fmaf(e, h[n], du * sB[l * 16 + n]);
            y = fmaf(h[n], sC[l * 16 + n], y);
        }
        yout[(size_t)(lbase + l) * 192 + d] = fmaf(u, Dp, y);
    }
}

// merge + LayerNorm + gate -> g (bf16, LDS) -> MFMA out GEMM. 32 pixels/block.
__global__ __launch_bounds__(256) void k_lnout(
        const float* __restrict__ yout, const float* __restrict__ z,
        const float* __restrict__ lng, const float* __restrict__ lnb,
        const unsigned short* __restrict__ Wo_bf, float* __restrict__ out) {
    __shared__ __align__(16) short sgb[32 * GSTRIDE];
    int p0 = blockIdx.x * 32;
    int t = threadIdx.x;
    int p = t >> 3;                    // pixel 0..31
    int sub = t & 7;                   // 8 threads per pixel, 24 channels each
    int gp = p0 + p;
    int b = gp >> 12;
    int hw = gp & 4095;
    int h = hw >> 6, w = hw & 63;
    int kq = (h & 1) ? ((w & 1) ? 3 : 1) : ((w & 1) ? 2 : 0);
    int l = (kq & 1) ? ((w >> 1) * 32 + (h >> 1))
                     : ((h >> 1) * 32 + (w >> 1));
    const float* yrow = yout + ((size_t)(b * 4 + kq) * 1024 + l) * 192 + sub * 24;
    float4 yv[6];
    float s = 0.0f, s2 = 0.0f;
    #pragma unroll
    for (int j = 0; j < 6; ++j) {
        float4 v = *(const float4*)(yrow + j * 4);
        yv[j] = v;
        s += v.x + v.y + v.z + v.w;
        s2 += v.x * v.x + v.y * v.y + v.z * v.z + v.w * v.w;
    }
    #pragma unroll
    for (int off = 1; off < 8; off <<= 1) {
        s  += __shfl_xor(s, off, 8);
        s2 += __shfl_xor(s2, off, 8);
    }
    float mu = s * (1.0f / 192.0f);
    float var = s2 * (1.0f / 192.0f) - mu * mu;
    float rstd = rsqrtf(var + 1e-5f);
    const float* zrow = z + (size_t)gp * 192 + sub * 24;
    short* grow = sgb + p * GSTRIDE + sub * 24;
    #pragma unroll
    for (int j = 0; j < 6; ++j) {
        float4 zv = *(const float4*)(zrow + j * 4);
        float4 gv = *(const float4*)(lng + sub * 24 + j * 4);
        float4 bv = *(const float4*)(lnb + sub * 24 + j * 4);
        short4v sv;
        sv.x = (short)f2bf(((yv[j].x - mu) * rstd * gv.x + bv.x) * zv.x);
        sv.y = (short)f2bf(((yv[j].y - mu) * rstd * gv.y + bv.y) * zv.y);
        sv.z = (short)f2bf(((yv[j].z - mu) * rstd * gv.z + bv.z) * zv.z);
        sv.w = (short)f2bf(((yv[j].w - mu) * rstd * gv.w + bv.w) * zv.w);
        *(short4v*)(grow + j * 4) = sv;
    }
    __syncthreads();
    // MFMA GEMM: out[32x96] = g @ W_out^T. wave w: M-tile w>>1, N-tiles (w&1)*3..+2
    int wv = t >> 6;
    int lane = t & 63;
    int m = lane & 15, quad = lane >> 4;
    int mt = wv >> 1;
    int nb = (wv & 1) * 3;
    const short* wob = (const short*)Wo_bf;
    short8 a[6];
    #pragma unroll
    for (int kk = 0; kk < 6; ++kk)
        a[kk] = *(const short8*)(sgb + (mt * 16 + m) * GSTRIDE + kk * 32 + quad * 8);
    #pragma unroll
    for (int i = 0; i < 3; ++i) {
        int n0 = (nb + i) * 16;
        f32x4 acc = {0.f, 0.f, 0.f, 0.f};
        #pragma unroll
        for (int kk = 0; kk < 6; ++kk) {
            short8 bfr = *(const short8*)(wob + (size_t)(n0 + m) * 192 + kk * 32 + quad * 8);
            acc = __builtin_amdgcn_mfma_f32_16x16x32_bf16(a[kk], bfr, acc, 0, 0, 0);
        }
        #pragma unroll
        for (int r = 0; r < 4; ++r) {
            int pp = p0 + mt * 16 + quad * 4 + r;
            out[(size_t)pp * 96 + n0 + m] = acc[r];
        }
    }
}

extern "C" void kernel_launch(void* const* d_in, const int* in_sizes, int n_in,
                              void* d_out, int out_size, void* d_ws, size_t ws_size,
                              hipStream_t stream) {
    const float* x    = (const float*)d_in[0];
    const float* W_in = (const float*)d_in[1];
    const float* cw   = (const float*)d_in[2];
    const float* cb   = (const float*)d_in[3];
    const float* xpw  = (const float*)d_in[4];
    const float* dtw  = (const float*)d_in[5];
    const float* dtb  = (const float*)d_in[6];
    const float* Alog = (const float*)d_in[7];
    const float* Ds   = (const float*)d_in[8];
    const float* lng  = (const float*)d_in[9];
    const float* lnb  = (const float*)d_in[10];
    const float* Wout = (const float*)d_in[11];
    float* out = (float*)d_out;

    float* ws = (float*)d_ws;
    size_t off = 0;
    float* WtIn  = ws + off; off += 96 * 384;
    unsigned short* Wo_bf = (unsigned short*)(ws + off); off += 96 * DINNER / 2;
    float* xin   = ws + off; off += (size_t)NPIX * 192;
    float* zbuf  = ws + off; off += (size_t)NPIX * 192;
    float* xg    = ws + off; off += (size_t)NPIX * 192;
    float* Pbuf  = ws + off; off += (size_t)NCH * NSTATES;
    float* QH    = ws + off; off += (size_t)NCH * NSTATES;
    float* yout  = ws + off; off += (size_t)NBK * LP * 192;

    hipLaunchKernelGGL(k_setup, dim3(144), dim3(256), 0, stream,
                       W_in, Wout, WtIn, Wo_bf);
    hipLaunchKernelGGL(k_inproj, dim3(NPIX / 32), dim3(256), 0, stream,
                       x, WtIn, xin, zbuf);
    hipLaunchKernelGGL(k_conv8, dim3(NPIX / 8), dim3(192), 0, stream,
                       xin, cw, cb, xg);
    hipLaunchKernelGGL(k_scan1g, dim3(NBK * NCH), dim3(192), 0, stream,
                       xg, xpw, Alog, dtw, dtb, Pbuf, QH);
    hipLaunchKernelGGL(k_scan2, dim3(NSTATES / 512), dim3(256), 0, stream,
                       Pbuf, QH);
    hipLaunchKernelGGL(k_scan3g, dim3(NBK * NCH), dim3(192), 0, stream,
                       xg, xpw, Alog, dtw, dtb, Ds, QH, yout);
    hipLaunchKernelGGL(k_lnout, dim3(NPIX / 32), dim3(256), 0, stream,
                       yout, zbuf, lng, lnb, Wo_bf, out);
}

// Round 9
// 180.971 us; speedup vs baseline: 1.6753x; 1.0821x over previous
//
#include <hip/hip_runtime.h>
#include <math.h>

// SS2D (VMamba v2) forward — MI355X gfx950.
// fp32 core; MFMA bf16-split in-proj (error-compensated); MFMA bf16 out-proj.
//
// Pipeline (7 dispatches):
//  k_cast    : x,W_in -> (hi,lo) bf16 pairs; W_out -> bf16
//  k_inproj3 : xz = x @ W_in^T via 3-term bf16 MFMA split -> xin, z=silu
//  k_conv8   : depthwise 3x3 SAME + bias + silu -> xg (scan order)
//  k_scan1g  : x_dbl GEMM into LDS (rows<22) + local scan -> S (sum dlt), Q
//  k_scan2   : prefix over 64 chunks; P recomputed as exp(A*S)
//  k_scan3g  : x_dbl GEMM recompute (38 rows) + replay with true h_in
//  k_lnout   : merge + LayerNorm + gate -> bf16 LDS -> MFMA out GEMM

#define DINNER 192
#define NSTATE 16
#define KDIR 4
#define BATCH 4
#define NPIX (BATCH * 64 * 64)          // 16384
#define LP 1024
#define NCH 64                          // scan chunks
#define CHUNK 16                        // LP / NCH
#define NBK (BATCH * KDIR)              // 16
#define NSTATES (NBK * DINNER * NSTATE) // 49152
#define SSTRIDE (NBK * DINNER)          // 3072 floats of S per chunk
#define USTRIDE 196                     // sU row stride (floats)
#define GSTRIDE 200                     // lnout bf16 g LDS stride (shorts)

typedef __attribute__((ext_vector_type(8))) short short8;
typedef __attribute__((ext_vector_type(4))) short short4v;
typedef __attribute__((ext_vector_type(4))) float f32x4;

__device__ __forceinline__ float silu_f(float x) {
    return x / (1.0f + __expf(-x));
}
__device__ __forceinline__ float softplus_f(float a) {
    return (a > 20.0f) ? a : __logf(1.0f + __expf(a));
}
__device__ __forceinline__ unsigned short f2bf(float f) {
    unsigned u = __float_as_uint(f);
    unsigned r = (u + 0x7FFFu + ((u >> 16) & 1u)) >> 16;
    return (unsigned short)r;
}
__device__ __forceinline__ float bf2f(unsigned short h) {
    return __uint_as_float(((unsigned)h) << 16);
}

// bf16 hi/lo splits of x and W_in (row-major), bf16 cast of W_out.
__global__ __launch_bounds__(256) void k_cast(
        const float* __restrict__ x, const float* __restrict__ W_in,
        const float* __restrict__ W_out,
        unsigned short* __restrict__ x_hi, unsigned short* __restrict__ x_lo,
        unsigned short* __restrict__ Wi_hi, unsigned short* __restrict__ Wi_lo,
        unsigned short* __restrict__ Wo_bf) {
    int i = blockIdx.x * 256 + threadIdx.x;
    if (i < NPIX * 96) {
        float v = x[i];
        unsigned short h = f2bf(v);
        x_hi[i] = h;
        x_lo[i] = f2bf(v - bf2f(h));
    }
    if (i < 384 * 96) {
        float v = W_in[i];
        unsigned short h = f2bf(v);
        Wi_hi[i] = h;
        Wi_lo[i] = f2bf(v - bf2f(h));
    }
    if (i < 96 * DINNER) Wo_bf[i] = f2bf(W_out[i]);
}

// MFMA in-proj (bf16x3 split): block = 16 pixels; wave w -> e-tiles w*6..w*6+5.
// A[m=lane&15][k=quad*8+j] = x[p0+m][c], B[k][n=lane&15] = W_in[e0+n][c].
// D: col=lane&15 (e), row=quad*4+reg (pixel).   err ~ x_lo*W_lo ~ 1e-5.
__global__ __launch_bounds__(256) void k_inproj3(
        const unsigned short* __restrict__ x_hi,
        const unsigned short* __restrict__ x_lo,
        const unsigned short* __restrict__ Wi_hi,
        const unsigned short* __restrict__ Wi_lo,
        float* __restrict__ xin, float* __restrict__ z) {
    int p0 = blockIdx.x * 16;
    int w = threadIdx.x >> 6;
    int lane = threadIdx.x & 63;
    int m = lane & 15, quad = lane >> 4;
    const short* xh = (const short*)x_hi;
    const short* xl = (const short*)x_lo;
    const short* wh = (const short*)Wi_hi;
    const short* wl = (const short*)Wi_lo;
    short8 ah[3], al[3];
    #pragma unroll
    for (int c = 0; c < 3; ++c) {
        size_t o = (size_t)(p0 + m) * 96 + c * 32 + quad * 8;
        ah[c] = *(const short8*)(xh + o);
        al[c] = *(const short8*)(xl + o);
    }
    #pragma unroll
    for (int i = 0; i < 6; ++i) {
        int e0 = (w * 6 + i) * 16;
        f32x4 acc = {0.f, 0.f, 0.f, 0.f};
        #pragma unroll
        for (int c = 0; c < 3; ++c) {
            size_t o = (size_t)(e0 + m) * 96 + c * 32 + quad * 8;
            short8 bh = *(const short8*)(wh + o);
            short8 bl = *(const short8*)(wl + o);
            acc = __builtin_amdgcn_mfma_f32_16x16x32_bf16(ah[c], bl, acc, 0, 0, 0);
            acc = __builtin_amdgcn_mfma_f32_16x16x32_bf16(al[c], bh, acc, 0, 0, 0);
            acc = __builtin_amdgcn_mfma_f32_16x16x32_bf16(ah[c], bh, acc, 0, 0, 0);
        }
        int e = e0 + m;
        #pragma unroll
        for (int r = 0; r < 4; ++r) {
            int p = p0 + quad * 4 + r;
            if (e < 192) xin[(size_t)p * 192 + e] = acc[r];
            else         z[(size_t)p * 192 + (e - 192)] = silu_f(acc[r]);
        }
    }
}

// depthwise 3x3, 8 consecutive pixels of one row per block; sliding-window loads.
// Output in scan order xg[(bk*1024+l)*192+d].
__global__ __launch_bounds__(192) void k_conv8(
        const float* __restrict__ xin, const float* __restrict__ cw,
        const float* __restrict__ cb, float* __restrict__ xg) {
    int blk = blockIdx.x;             // 2048 = 4 b * 64 h * 8 wchunks
    int b = blk >> 9;
    int rem = blk & 511;
    int h = rem >> 3;
    int w0 = (rem & 7) * 8;
    int d = threadIdx.x;
    float wr[3][3];
    #pragma unroll
    for (int i = 0; i < 3; ++i)
        #pragma unroll
        for (int j = 0; j < 3; ++j) wr[i][j] = cw[d * 9 + i * 3 + j];
    float bias = cb[d];
    float acc[8];
    #pragma unroll
    for (int o = 0; o < 8; ++o) acc[o] = bias;
    #pragma unroll
    for (int jj = 0; jj < 10; ++jj) {
        int ww = w0 + jj - 1;
        float r0 = 0.0f, r1 = 0.0f, r2 = 0.0f;
        if ((unsigned)ww < 64u) {
            const float* base = xin + ((size_t)b * 4096 + h * 64 + ww) * 192 + d;
            if (h > 0)  r0 = base[-64 * 192];
            r1 = base[0];
            if (h < 63) r2 = base[64 * 192];
        }
        #pragma unroll
        for (int dd2 = 0; dd2 < 3; ++dd2) {
            int o = jj - 2 + dd2;
            int cj = 2 - dd2;
            if (o >= 0 && o < 8) {
                acc[o] = fmaf(r0, wr[0][cj], acc[o]);
                acc[o] = fmaf(r1, wr[1][cj], acc[o]);
                acc[o] = fmaf(r2, wr[2][cj], acc[o]);
            }
        }
    }
    #pragma unroll
    for (int o = 0; o < 8; ++o) {
        int w = w0 + o;
        int kq = (h & 1) ? ((w & 1) ? 3 : 1) : ((w & 1) ? 2 : 0);
        int l = (kq & 1) ? ((w >> 1) * 32 + (h >> 1))
                         : ((h >> 1) * 32 + (w >> 1));
        xg[((size_t)(b * 4 + kq) * 1024 + l) * 192 + d] = silu_f(acc[o]);
    }
}

// Pass 1 (fused x_dbl): u tile + GEMM rows<22 into LDS, local scan.
// Emits Q (chunk-local h) and S = sum(dlt) per (ch, bk, d)  [P = exp(A*S)].
__global__ __launch_bounds__(192) void k_scan1g(
        const float* __restrict__ xg, const float* __restrict__ xpw,
        const float* __restrict__ A_logs, const float* __restrict__ dtw,
        const float* __restrict__ dtb,
        float* __restrict__ Sbuf, float* __restrict__ Qbuf) {
    __shared__ float sU[CHUNK * USTRIDE];
    __shared__ float sB[CHUNK * 16];
    __shared__ float sR[CHUNK * 8];
    int bk = blockIdx.x >> 6;
    int ch = blockIdx.x & 63;
    int k = bk & 3;
    int t = threadIdx.x;
    int d = t;
    int lbase = bk * 1024 + ch * CHUNK;
    const float4* usrc = (const float4*)(xg + (size_t)lbase * 192);
    for (int i = t; i < CHUNK * 48; i += 192) {
        int l = i / 48, c4 = i - l * 48;
        *(float4*)&sU[l * USTRIDE + c4 * 4] = usrc[i];
    }
    float A[16];
    #pragma unroll
    for (int n = 0; n < 16; ++n) A[n] = -__expf(A_logs[(k * 192 + d) * 16 + n]);
    float A0 = A[0];
    bool geo = true;                 // A[n] == (n+1)*A[0] (geometric ladder)?
    #pragma unroll
    for (int n = 1; n < 16; ++n)
        geo = geo && (fabsf(A[n] - (float)(n + 1) * A0) <= 1e-4f * fabsf(A[n]));
    float wp[6];
    #pragma unroll
    for (int q = 0; q < 6; ++q) wp[q] = dtw[(k * 192 + d) * 6 + q];
    float bias = dtb[k * 192 + d];
    __syncthreads();
    {
        int l = t & 15, cgp = t >> 4;       // 16 l x 12 c-groups
        float acc0 = 0.0f, acc1 = 0.0f;
        const float* wb = xpw + (size_t)k * 38 * 192;
        int c1 = cgp + 12;
        int c1r = (c1 < 22) ? c1 : cgp;
        for (int qv = 0; qv < 48; ++qv) {
            float4 xv = *(const float4*)&sU[l * USTRIDE + qv * 4];
            float4 w0 = *(const float4*)&wb[(size_t)cgp * 192 + qv * 4];
            float4 w1 = *(const float4*)&wb[(size_t)c1r * 192 + qv * 4];
            acc0 = fmaf(xv.x, w0.x, fmaf(xv.y, w0.y, fmaf(xv.z, w0.z, fmaf(xv.w, w0.w, acc0))));
            acc1 = fmaf(xv.x, w1.x, fmaf(xv.y, w1.y, fmaf(xv.z, w1.z, fmaf(xv.w, w1.w, acc1))));
        }
        if (cgp < 6) sR[l * 8 + cgp] = acc0;
        else         sB[l * 16 + (cgp - 6)] = acc0;
        if (c1 < 22) sB[l * 16 + (c1 - 6)] = acc1;
    }
    __syncthreads();
    float h[16];
    #pragma unroll
    for (int n = 0; n < 16; ++n) h[n] = 0.0f;
    float S = 0.0f;
    for (int l = 0; l < CHUNK; ++l) {
        float a = bias;
        #pragma unroll
        for (int q = 0; q < 6; ++q) a = fmaf(wp[q], sR[l * 8 + q], a);
        float dlt = softplus_f(a);
        S += dlt;
        float du = dlt * sU[l * USTRIDE + d];
        if (geo) {
            float e1 = __expf(dlt * A0);
            float e = e1;
            #pragma unroll
            for (int n = 0; n < 16; ++n) {
                h[n] = fmaf(e, h[n], du * sB[l * 16 + n]);
                e *= e1;
            }
        } else {
            #pragma unroll
            for (int n = 0; n < 16; ++n) {
                float e = __expf(dlt * A[n]);
                h[n] = fmaf(e, h[n], du * sB[l * 16 + n]);
            }
        }
    }
    Sbuf[(size_t)ch * SSTRIDE + bk * 192 + d] = S;
    size_t base = (size_t)ch * NSTATES + bk * (192 * 16);
    #pragma unroll
    for (int n = 0; n < 16; ++n)
        Qbuf[base + n * 192 + d] = h[n];
}

// Pass 2: prefix over chunks; P recomputed as exp(A*S). In place (QH -> h_start).
__global__ __launch_bounds__(256) void k_scan2(
        const float* __restrict__ Sbuf, const float* __restrict__ A_logs,
        float* QH) {
    int s = blockIdx.x * 256 + threadIdx.x;   // 0..NSTATES-1
    int bk = s / 3072;                         // 3072 = 16*192
    int rem = s - bk * 3072;
    int n = rem / 192;
    int d = rem - n * 192;
    int k = bk & 3;
    float A = -__expf(A_logs[(k * 192 + d) * 16 + n]);
    float h = 0.0f;
    for (int c = 0; c < NCH; ++c) {
        float q = QH[(size_t)c * NSTATES + s];
        float S = Sbuf[(size_t)c * SSTRIDE + bk * 192 + d];
        float p = __expf(A * S);
        QH[(size_t)c * NSTATES + s] = h;
        h = fmaf(p, h, q);
    }
}

// Pass 3 (fused x_dbl): GEMM recompute (all 38 rows), replay with true h_in.
__global__ __launch_bounds__(192) void k_scan3g(
        const float* __restrict__ xg, const float* __restrict__ xpw,
        const float* __restrict__ A_logs, const float* __restrict__ dtw,
        const float* __restrict__ dtb, const float* __restrict__ Ds,
        const float* __restrict__ QH, float* __restrict__ yout) {
    __shared__ float sU[CHUNK * USTRIDE];
    __shared__ float sB[CHUNK * 16];
    __shared__ float sC[CHUNK * 16];
    __shared__ float sR[CHUNK * 8];
    int bk = blockIdx.x >> 6;
    int ch = blockIdx.x & 63;
    int k = bk & 3;
    int t = threadIdx.x;
    int d = t;
    int lbase = bk * 1024 + ch * CHUNK;
    const float4* usrc = (const float4*)(xg + (size_t)lbase * 192);
    for (int i = t; i < CHUNK * 48; i += 192) {
        int l = i / 48, c4 = i - l * 48;
        *(float4*)&sU[l * USTRIDE + c4 * 4] = usrc[i];
    }
    float A[16];
    #pragma unroll
    for (int n = 0; n < 16; ++n) A[n] = -__expf(A_logs[(k * 192 + d) * 16 + n]);
    float A0 = A[0];
    bool geo = true;
    #pragma unroll
    for (int n = 1; n < 16; ++n)
        geo = geo && (fabsf(A[n] - (float)(n + 1) * A0) <= 1e-4f * fabsf(A[n]));
    float wp[6];
    #pragma unroll
    for (int q = 0; q < 6; ++q) wp[q] = dtw[(k * 192 + d) * 6 + q];
    float bias = dtb[k * 192 + d];
    float Dp = Ds[k * 192 + d];
    __syncthreads();
    {
        int l = t & 15, cgp = t >> 4;
        float acc[4] = {0.f, 0.f, 0.f, 0.f};
        int c3 = (cgp < 2) ? (cgp + 36) : cgp;
        const float* wb = xpw + (size_t)k * 38 * 192;
        for (int qv = 0; qv < 48; ++qv) {
            float4 xv = *(const float4*)&sU[l * USTRIDE + qv * 4];
            float4 w0 = *(const float4*)&wb[(cgp +  0) * 192 + qv * 4];
            float4 w1 = *(const float4*)&wb[(cgp + 12) * 192 + qv * 4];
            float4 w2 = *(const float4*)&wb[(cgp + 24) * 192 + qv * 4];
            float4 w3 = *(const float4*)&wb[(size_t)c3 * 192 + qv * 4];
            acc[0] = fmaf(xv.x, w0.x, fmaf(xv.y, w0.y, fmaf(xv.z, w0.z, fmaf(xv.w, w0.w, acc[0]))));
            acc[1] = fmaf(xv.x, w1.x, fmaf(xv.y, w1.y, fmaf(xv.z, w1.z, fmaf(xv.w, w1.w, acc[1]))));
            acc[2] = fmaf(xv.x, w2.x, fmaf(xv.y, w2.y, fmaf(xv.z, w2.z, fmaf(xv.w, w2.w, acc[2]))));
            acc[3] = fmaf(xv.x, w3.x, fmaf(xv.y, w3.y, fmaf(xv.z, w3.z, fmaf(xv.w, w3.w, acc[3]))));
        }
        #pragma unroll
        for (int j = 0; j < 4; ++j) {
            int c = cgp + 12 * j;
            if (j == 3) { if (cgp >= 2) break; c = cgp + 36; }
            float v = acc[j];
            if (c < 6)       sR[l * 8 + c] = v;
            else if (c < 22) sB[l * 16 + (c - 6)] = v;
            else             sC[l * 16 + (c - 22)] = v;
        }
    }
    float h[16];
    size_t base = (size_t)ch * NSTATES + bk * (192 * 16);
    #pragma unroll
    for (int n = 0; n < 16; ++n) h[n] = QH[base + n * 192 + d];
    __syncthreads();
    for (int l = 0; l < CHUNK; ++l) {
        float a = bias;
        #pragma unroll
        for (int q = 0; q < 6; ++q) a = fmaf(wp[q], sR[l * 8 + q], a);
        float dlt = softplus_f(a);
        float u = sU[l * USTRIDE + d];
        float du = dlt * u;
        float y = 0.0f;
        if (geo) {
            float e1 = __expf(dlt * A0);
            float e = e1;
            #pragma unroll
            for (int n = 0; n < 16; ++n) {
                h[n] = fmaf(e, h[n], du * sB[l * 16 + n]);
                y = fmaf(h[n], sC[l * 16 + n], y);
                e *= e1;
            }
        } else {
            #pragma unroll
            for (int n = 0; n < 16; ++n) {
                float e = __expf(dlt * A[n]);
                h[n] = fmaf(e, h[n], du * sB[l * 16 + n]);
                y = fmaf(h[n], sC[l * 16 + n], y);
            }
        }
        yout[(size_t)(lbase + l) * 192 + d] = fmaf(u, Dp, y);
    }
}

// merge + LayerNorm + gate -> g (bf16, LDS) -> MFMA out GEMM. 32 pixels/block.
__global__ __launch_bounds__(256) void k_lnout(
        const float* __restrict__ yout, const float* __restrict__ z,
        const float* __restrict__ lng, const float* __restrict__ lnb,
        const unsigned short* __restrict__ Wo_bf, float* __restrict__ out) {
    __shared__ __align__(16) short sgb[32 * GSTRIDE];
    int p0 = blockIdx.x * 32;
    int t = threadIdx.x;
    int p = t >> 3;                    // pixel 0..31
    int sub = t & 7;                   // 8 threads per pixel, 24 channels each
    int gp = p0 + p;
    int b = gp >> 12;
    int hw = gp & 4095;
    int h = hw >> 6, w = hw & 63;
    int kq = (h & 1) ? ((w & 1) ? 3 : 1) : ((w & 1) ? 2 : 0);
    int l = (kq & 1) ? ((w >> 1) * 32 + (h >> 1))
                     : ((h >> 1) * 32 + (w >> 1));
    const float* yrow = yout + ((size_t)(b * 4 + kq) * 1024 + l) * 192 + sub * 24;
    float4 yv[6];
    float s = 0.0f, s2 = 0.0f;
    #pragma unroll
    for (int j = 0; j < 6; ++j) {
        float4 v = *(const float4*)(yrow + j * 4);
        yv[j] = v;
        s += v.x + v.y + v.z + v.w;
        s2 += v.x * v.x + v.y * v.y + v.z * v.z + v.w * v.w;
    }
    #pragma unroll
    for (int off = 1; off < 8; off <<= 1) {
        s  += __shfl_xor(s, off, 8);
        s2 += __shfl_xor(s2, off, 8);
    }
    float mu = s * (1.0f / 192.0f);
    float var = s2 * (1.0f / 192.0f) - mu * mu;
    float rstd = rsqrtf(var + 1e-5f);
    const float* zrow = z + (size_t)gp * 192 + sub * 24;
    short* grow = sgb + p * GSTRIDE + sub * 24;
    #pragma unroll
    for (int j = 0; j < 6; ++j) {
        float4 zv = *(const float4*)(zrow + j * 4);
        float4 gv = *(const float4*)(lng + sub * 24 + j * 4);
        float4 bv = *(const float4*)(lnb + sub * 24 + j * 4);
        short4v sv;
        sv.x = (short)f2bf(((yv[j].x - mu) * rstd * gv.x + bv.x) * zv.x);
        sv.y = (short)f2bf(((yv[j].y - mu) * rstd * gv.y + bv.y) * zv.y);
        sv.z = (short)f2bf(((yv[j].z - mu) * rstd * gv.z + bv.z) * zv.z);
        sv.w = (short)f2bf(((yv[j].w - mu) * rstd * gv.w + bv.w) * zv.w);
        *(short4v*)(grow + j * 4) = sv;
    }
    __syncthreads();
    // MFMA GEMM: out[32x96] = g @ W_out^T. wave w: M-tile w>>1, N-tiles (w&1)*3..+2
    int wv = t >> 6;
    int lane = t & 63;
    int m = lane & 15, quad = lane >> 4;
    int mt = wv >> 1;
    int nb = (wv & 1) * 3;
    const short* wob = (const short*)Wo_bf;
    short8 a[6];
    #pragma unroll
    for (int kk = 0; kk < 6; ++kk)
        a[kk] = *(const short8*)(sgb + (mt * 16 + m) * GSTRIDE + kk * 32 + quad * 8);
    #pragma unroll
    for (int i = 0; i < 3; ++i) {
        int n0 = (nb + i) * 16;
        f32x4 acc = {0.f, 0.f, 0.f, 0.f};
        #pragma unroll
        for (int kk = 0; kk < 6; ++kk) {
            short8 bfr = *(const short8*)(wob + (size_t)(n0 + m) * 192 + kk * 32 + quad * 8);
            acc = __builtin_amdgcn_mfma_f32_16x16x32_bf16(a[kk], bfr, acc, 0, 0, 0);
        }
        #pragma unroll
        for (int r = 0; r < 4; ++r) {
            int pp = p0 + mt * 16 + quad * 4 + r;
            out[(size_t)pp * 96 + n0 + m] = acc[r];
        }
    }
}

extern "C" void kernel_launch(void* const* d_in, const int* in_sizes, int n_in,
                              void* d_out, int out_size, void* d_ws, size_t ws_size,
                              hipStream_t stream) {
    const float* x    = (const float*)d_in[0];
    const float* W_in = (const float*)d_in[1];
    const float* cw   = (const float*)d_in[2];
    const float* cb   = (const float*)d_in[3];
    const float* xpw  = (const float*)d_in[4];
    const float* dtw  = (const float*)d_in[5];
    const float* dtb  = (const float*)d_in[6];
    const float* Alog = (const float*)d_in[7];
    const float* Ds   = (const float*)d_in[8];
    const float* lng  = (const float*)d_in[9];
    const float* lnb  = (const float*)d_in[10];
    const float* Wout = (const float*)d_in[11];
    float* out = (float*)d_out;

    float* ws = (float*)d_ws;
    size_t off = 0;
    unsigned short* x_hi  = (unsigned short*)(ws + off); off += NPIX * 96 / 2;
    unsigned short* x_lo  = (unsigned short*)(ws + off); off += NPIX * 96 / 2;
    unsigned short* Wi_hi = (unsigned short*)(ws + off); off += 384 * 96 / 2;
    unsigned short* Wi_lo = (unsigned short*)(ws + off); off += 384 * 96 / 2;
    unsigned short* Wo_bf = (unsigned short*)(ws + off); off += 96 * DINNER / 2;
    float* xin   = ws + off; off += (size_t)NPIX * 192;
    float* zbuf  = ws + off; off += (size_t)NPIX * 192;
    float* xg    = ws + off; off += (size_t)NPIX * 192;
    float* Sbuf  = ws + off; off += (size_t)NCH * SSTRIDE;
    float* QH    = ws + off; off += (size_t)NCH * NSTATES;
    float* yout  = ws + off; off += (size_t)NBK * LP * 192;

    hipLaunchKernelGGL(k_cast, dim3((NPIX * 96 + 255) / 256), dim3(256), 0, stream,
                       x, W_in, Wout, x_hi, x_lo, Wi_hi, Wi_lo, Wo_bf);
    hipLaunchKernelGGL(k_inproj3, dim3(NPIX / 16), dim3(256), 0, stream,
                       x_hi, x_lo, Wi_hi, Wi_lo, xin, zbuf);
    hipLaunchKernelGGL(k_conv8, dim3(NPIX / 8), dim3(192), 0, stream,
                       xin, cw, cb, xg);
    hipLaunchKernelGGL(k_scan1g, dim3(NBK * NCH), dim3(192), 0, stream,
                       xg, xpw, Alog, dtw, dtb, Sbuf, QH);
    hipLaunchKernelGGL(k_scan2, dim3(NSTATES / 256), dim3(256), 0, stream,
                       Sbuf, Alog, QH);
    hipLaunchKernelGGL(k_scan3g, dim3(NBK * NCH), dim3(192), 0, stream,
                       xg, xpw, Alog, dtw, dtb, Ds, QH, yout);
    hipLaunchKernelGGL(k_lnout, dim3(NPIX / 32), dim3(256), 0, stream,
                       yout, zbuf, lng, lnb, Wo_bf, out);
}